// Round 1
// baseline (4103.263 us; speedup 1.0000x reference)
//
#include <hip/hip_runtime.h>
#include <math.h>

// Problem constants (match reference)
#define NN 50000
#define NE 800000

// ---------------- zero-init kernel ----------------
__global__ void zero_kernel(float4* __restrict__ p, int n4) {
    int i = blockIdx.x * blockDim.x + threadIdx.x;
    int s = gridDim.x * blockDim.x;
    float4 z = make_float4(0.f, 0.f, 0.f, 0.f);
    for (; i < n4; i += s) p[i] = z;
}

// ---------------- EdgeConv: msg = relu([x_dst, x_src - x_dst] @ W + b),
//                   agg[dst] = max(agg[dst], msg)  (agg pre-zeroed; msg>=0) ----
template<int IN, int OUT>
__global__ __launch_bounds__(256, 2)
void edgeconv_kernel(const float* __restrict__ X,
                     const int* __restrict__ esrc,
                     const int* __restrict__ edst,
                     int istride,
                     const float* __restrict__ W,
                     const float* __restrict__ b,
                     float* __restrict__ agg,
                     int nE)
{
    constexpr int K  = 2 * IN;
    constexpr int BE = 32;          // edges per block
    constexpr int BK = 32;          // K-chunk for W staging
    constexpr int ME = 2;           // edges per thread
    constexpr int NQ = OUT / 64;    // 64-col groups per thread (OUT in {64,128,256})
    constexpr int MO = NQ * 4;      // outs per thread

    __shared__ float feat[BE][K + 4];
    __shared__ float wl[BK][OUT];
    __shared__ int   sdst[BE];
    __shared__ int   ssrc[BE];

    const int t  = threadIdx.x;
    const int e0 = blockIdx.x * BE;

    // stage edge indices (low word handles both int32 and little-endian int64)
    if (t < BE) {
        int e = min(e0 + t, nE - 1);
        sdst[t] = edst[(size_t)e * istride];
    } else if (t < 2 * BE) {
        int tt = t - BE;
        int e = min(e0 + tt, nE - 1);
        ssrc[tt] = esrc[(size_t)e * istride];
    }
    __syncthreads();

    // gather + concat features into LDS: feat[e][0:IN]=x_dst, feat[e][IN:2IN]=x_src-x_dst
    constexpr int C4 = IN / 4;
    for (int i = t; i < BE * C4; i += 256) {
        int e = i / C4;
        int c = (i % C4) * 4;
        const float4 xi = *(const float4*)(X + (size_t)sdst[e] * IN + c);
        const float4 xj = *(const float4*)(X + (size_t)ssrc[e] * IN + c);
        *(float4*)(&feat[e][c]) = xi;
        *(float4*)(&feat[e][IN + c]) =
            make_float4(xj.x - xi.x, xj.y - xi.y, xj.z - xi.z, xj.w - xi.w);
    }

    const int te = t >> 4;   // 0..15  (edge group)
    const int to = t & 15;   // 0..15  (out group)

    float acc[ME][MO];
#pragma unroll
    for (int me = 0; me < ME; ++me)
#pragma unroll
        for (int mo = 0; mo < MO; ++mo) acc[me][mo] = 0.f;

    for (int kk = 0; kk < K; kk += BK) {
        __syncthreads();   // protect wl from previous chunk's readers; covers feat staging on iter 0
        // stage W rows kk..kk+BK (contiguous in global)
        for (int i = t * 4; i < BK * OUT; i += 1024) {
            *(float4*)(&wl[0][0] + i) = *(const float4*)(W + (size_t)kk * OUT + i);
        }
        __syncthreads();

#pragma unroll 4
        for (int k = 0; k < BK; ++k) {
            float f[ME];
#pragma unroll
            for (int me = 0; me < ME; ++me) f[me] = feat[te * ME + me][kk + k];
#pragma unroll
            for (int q = 0; q < NQ; ++q) {
                const float4 w4 = *(const float4*)(&wl[k][to * 4 + q * 64]);
#pragma unroll
                for (int me = 0; me < ME; ++me) {
                    acc[me][q * 4 + 0] = fmaf(f[me], w4.x, acc[me][q * 4 + 0]);
                    acc[me][q * 4 + 1] = fmaf(f[me], w4.y, acc[me][q * 4 + 1]);
                    acc[me][q * 4 + 2] = fmaf(f[me], w4.z, acc[me][q * 4 + 2]);
                    acc[me][q * 4 + 3] = fmaf(f[me], w4.w, acc[me][q * 4 + 3]);
                }
            }
        }
    }

    // epilogue: bias + relu + atomicMax into agg[dst]
#pragma unroll
    for (int me = 0; me < ME; ++me) {
        int le = te * ME + me;
        int e  = e0 + le;
        if (e < nE) {
            size_t base = (size_t)sdst[le] * OUT;
#pragma unroll
            for (int q = 0; q < NQ; ++q) {
#pragma unroll
                for (int r = 0; r < 4; ++r) {
                    int o = to * 4 + q * 64 + r;
                    float v = acc[me][q * 4 + r] + b[o];
                    if (v > 0.f) {
                        atomicMax((unsigned int*)agg + base + o, __float_as_uint(v));
                    }
                }
            }
        }
    }
}

// ---------------- MLP head: out = sigmoid(relu(H @ Wf1 + bf1) @ Wf2 + bf2) ----
__global__ __launch_bounds__(256, 2)
void mlp_head_kernel(const float* __restrict__ H,
                     const float* __restrict__ Wf1,
                     const float* __restrict__ bf1,
                     const float* __restrict__ Wf2,
                     const float* __restrict__ bf2,
                     float* __restrict__ out,
                     int nNodes)
{
    constexpr int K = 256, OUT = 256, BN = 32, BK = 32, ME = 2, NQ = OUT / 64, MO = NQ * 4;
    __shared__ float feat[BN][K + 4];
    __shared__ float wl[BK][OUT];

    const int t  = threadIdx.x;
    const int n0 = blockIdx.x * BN;

    constexpr int C4 = K / 4;
    for (int i = t; i < BN * C4; i += 256) {
        int n = i / C4;
        int c = (i % C4) * 4;
        int nn = min(n0 + n, nNodes - 1);
        *(float4*)(&feat[n][c]) = *(const float4*)(H + (size_t)nn * K + c);
    }

    const int te = t >> 4;
    const int to = t & 15;

    float acc[ME][MO];
#pragma unroll
    for (int me = 0; me < ME; ++me)
#pragma unroll
        for (int mo = 0; mo < MO; ++mo) acc[me][mo] = 0.f;

    for (int kk = 0; kk < K; kk += BK) {
        __syncthreads();
        for (int i = t * 4; i < BK * OUT; i += 1024) {
            *(float4*)(&wl[0][0] + i) = *(const float4*)(Wf1 + (size_t)kk * OUT + i);
        }
        __syncthreads();
#pragma unroll 4
        for (int k = 0; k < BK; ++k) {
            float f[ME];
#pragma unroll
            for (int me = 0; me < ME; ++me) f[me] = feat[te * ME + me][kk + k];
#pragma unroll
            for (int q = 0; q < NQ; ++q) {
                const float4 w4 = *(const float4*)(&wl[k][to * 4 + q * 64]);
#pragma unroll
                for (int me = 0; me < ME; ++me) {
                    acc[me][q * 4 + 0] = fmaf(f[me], w4.x, acc[me][q * 4 + 0]);
                    acc[me][q * 4 + 1] = fmaf(f[me], w4.y, acc[me][q * 4 + 1]);
                    acc[me][q * 4 + 2] = fmaf(f[me], w4.z, acc[me][q * 4 + 2]);
                    acc[me][q * 4 + 3] = fmaf(f[me], w4.w, acc[me][q * 4 + 3]);
                }
            }
        }
    }

    // fc2: per-thread partial dot over its 16 outs, then reduce across the 16 `to` lanes
    float part[ME] = {0.f, 0.f};
#pragma unroll
    for (int q = 0; q < NQ; ++q) {
#pragma unroll
        for (int r = 0; r < 4; ++r) {
            int o = to * 4 + q * 64 + r;
            float w2 = Wf2[o];
            float bb = bf1[o];
#pragma unroll
            for (int me = 0; me < ME; ++me) {
                float v = fmaxf(acc[me][q * 4 + r] + bb, 0.f);
                part[me] = fmaf(v, w2, part[me]);
            }
        }
    }
#pragma unroll
    for (int s = 8; s >= 1; s >>= 1) {
        part[0] += __shfl_xor(part[0], s, 16);
        part[1] += __shfl_xor(part[1], s, 16);
    }
    if (to == 0) {
#pragma unroll
        for (int me = 0; me < ME; ++me) {
            int n = n0 + te * ME + me;
            if (n < nNodes) {
                float x = part[me] + bf2[0];
                out[n] = 1.f / (1.f + expf(-x));
            }
        }
    }
}

// ---------------- launch ----------------
extern "C" void kernel_launch(void* const* d_in, const int* in_sizes, int n_in,
                              void* d_out, int out_size, void* d_ws, size_t ws_size,
                              hipStream_t stream) {
    const float* X   = (const float*)d_in[0];
    const int*   ei  = (const int*)d_in[1];
    const float* W1  = (const float*)d_in[2];
    const float* b1  = (const float*)d_in[3];
    const float* W2  = (const float*)d_in[4];
    const float* b2  = (const float*)d_in[5];
    const float* W3  = (const float*)d_in[6];
    const float* b3  = (const float*)d_in[7];
    const float* Wf1 = (const float*)d_in[8];
    const float* bf1 = (const float*)d_in[9];
    const float* Wf2 = (const float*)d_in[10];
    const float* bf2 = (const float*)d_in[11];
    float* out = (float*)d_out;

    // edge_index may arrive as int32 (2E elements) or raw int64 (counted as 4E int32)
    int istride = (in_sizes[1] == 4 * NE) ? 2 : 1;
    const int* esrc = ei;
    const int* edst = ei + (size_t)NE * istride;

    float* A = (float*)d_ws;                    // holds H1 then H3  (N*256 floats)
    float* B = A + (size_t)NN * 256;            // holds H2 then (unused)  (N*256 floats)

    const int ZB = 256;
    auto zgrid = [](int n4) { int g = (n4 + 255) / 256; return g > 4096 ? 4096 : g; };

    // layer 1: X[N,16] -> A[N,64]
    zero_kernel<<<zgrid(NN * 64 / 4), ZB, 0, stream>>>((float4*)A, NN * 64 / 4);
    edgeconv_kernel<16, 64><<<NE / 32, 256, 0, stream>>>(X, esrc, edst, istride, W1, b1, A, NE);

    // layer 2: A[N,64] -> B[N,128]
    zero_kernel<<<zgrid(NN * 128 / 4), ZB, 0, stream>>>((float4*)B, NN * 128 / 4);
    edgeconv_kernel<64, 128><<<NE / 32, 256, 0, stream>>>(A, esrc, edst, istride, W2, b2, B, NE);

    // layer 3: B[N,128] -> A[N,256]
    zero_kernel<<<zgrid(NN * 256 / 4), ZB, 0, stream>>>((float4*)A, NN * 256 / 4);
    edgeconv_kernel<128, 256><<<NE / 32, 256, 0, stream>>>(B, esrc, edst, istride, W3, b3, A, NE);

    // MLP head: A[N,256] -> out[N]
    mlp_head_kernel<<<(NN + 31) / 32, 256, 0, stream>>>(A, Wf1, bf1, Wf2, bf2, out, NN);
}

// Round 2
// 716.194 us; speedup vs baseline: 5.7293x; 5.7293x over previous
//
#include <hip/hip_runtime.h>
#include <math.h>

#define NN 50000
#define NE 800000

// ---------------- zero int buffer ----------------
__global__ void zeroi_kernel(int* __restrict__ p, int n) {
    int i = blockIdx.x * blockDim.x + threadIdx.x;
    int s = gridDim.x * blockDim.x;
    for (; i < n; i += s) p[i] = 0;
}

// ---------------- CSR build: histogram ----------------
__global__ void hist_kernel(const int* __restrict__ edst, int istride,
                            int* __restrict__ deg, int nE) {
    int i = blockIdx.x * blockDim.x + threadIdx.x;
    int s = gridDim.x * blockDim.x;
    for (; i < nE; i += s) atomicAdd(&deg[edst[(size_t)i * istride]], 1);
}

// ---------------- CSR build: single-block exclusive scan ----------------
// reads deg[], writes rowptr[] (exclusive) and rewrites deg[] as cursor (=rowptr)
__global__ __launch_bounds__(1024)
void scan_kernel(int* __restrict__ deg, int* __restrict__ rowptr, int n) {
    __shared__ int sums[1024];
    const int t = threadIdx.x;
    const int chunk = (n + 1023) >> 10;
    const int lo = t * chunk;
    const int hi = min(lo + chunk, n);
    int s = 0;
    for (int i = lo; i < hi; ++i) s += deg[i];
    sums[t] = s;
    __syncthreads();
    for (int off = 1; off < 1024; off <<= 1) {
        int v = 0;
        if (t >= off) v = sums[t - off];
        __syncthreads();
        if (t >= off) sums[t] += v;
        __syncthreads();
    }
    int run = sums[t] - s;   // exclusive base
    for (int i = lo; i < hi; ++i) {
        int c = deg[i];
        rowptr[i] = run;
        deg[i] = run;        // cursor for scatter
        run += c;
    }
    if (hi == n) rowptr[n] = run;
}

// ---------------- CSR build: scatter src by dst ----------------
__global__ void scatter_kernel(const int* __restrict__ esrc, const int* __restrict__ edst,
                               int istride, int* __restrict__ cursor,
                               int* __restrict__ col, int nE) {
    int i = blockIdx.x * blockDim.x + threadIdx.x;
    int s = gridDim.x * blockDim.x;
    for (; i < nE; i += s) {
        int d = edst[(size_t)i * istride];
        int pos = atomicAdd(&cursor[d], 1);
        col[pos] = esrc[(size_t)i * istride];
    }
}

// ---------------- weight prep: Wmod[IN][2*OUT] = [Wa-Wb | Wb] ----------------
__global__ void prepw_kernel(const float* __restrict__ W, float* __restrict__ Wm,
                             int IN, int OUT) {
    int idx = blockIdx.x * blockDim.x + threadIdx.x;
    if (idx >= IN * OUT) return;
    int k = idx / OUT, o = idx % OUT;
    float wa = W[(size_t)k * OUT + o];
    float wb = W[(size_t)(k + IN) * OUT + o];
    Wm[(size_t)k * 2 * OUT + o] = wa - wb;
    Wm[(size_t)k * 2 * OUT + OUT + o] = wb;
}

// ---------------- node GEMM: PQ[n, KO] = H[n, K] @ Wm[K, KO] ----------------
template<int K>
__global__ __launch_bounds__(256, 4)
void gemm_kernel(const float* __restrict__ H, const float* __restrict__ Wm,
                 float* __restrict__ PQ, int n, int KO) {
    constexpr int BK = (K < 32) ? K : 32;
    __shared__ float feat[32][K + 4];
    __shared__ float wl[BK][128];

    const int t = threadIdx.x;
    const int n0 = blockIdx.x * 32;
    const int col0 = blockIdx.y * 128;

    constexpr int C4 = K / 4;
    for (int i = t; i < 32 * C4; i += 256) {
        int e = i / C4, c = (i % C4) * 4;
        int nn = min(n0 + e, n - 1);
        *(float4*)(&feat[e][c]) = *(const float4*)(H + (size_t)nn * K + c);
    }

    const int te = t >> 4;   // node pair group
    const int to = t & 15;   // col group

    float acc[2][8];
#pragma unroll
    for (int me = 0; me < 2; ++me)
#pragma unroll
        for (int mo = 0; mo < 8; ++mo) acc[me][mo] = 0.f;

    for (int kk = 0; kk < K; kk += BK) {
        __syncthreads();
        for (int i = t * 4; i < BK * 128; i += 1024) {
            int r = i >> 7, c = i & 127;
            *(float4*)(&wl[r][c]) = *(const float4*)(Wm + (size_t)(kk + r) * KO + col0 + c);
        }
        __syncthreads();
#pragma unroll
        for (int k = 0; k < BK; ++k) {
            float f0 = feat[te * 2 + 0][kk + k];
            float f1 = feat[te * 2 + 1][kk + k];
#pragma unroll
            for (int q = 0; q < 2; ++q) {
                const float4 w4 = *(const float4*)(&wl[k][to * 4 + q * 64]);
                acc[0][q * 4 + 0] = fmaf(f0, w4.x, acc[0][q * 4 + 0]);
                acc[0][q * 4 + 1] = fmaf(f0, w4.y, acc[0][q * 4 + 1]);
                acc[0][q * 4 + 2] = fmaf(f0, w4.z, acc[0][q * 4 + 2]);
                acc[0][q * 4 + 3] = fmaf(f0, w4.w, acc[0][q * 4 + 3]);
                acc[1][q * 4 + 0] = fmaf(f1, w4.x, acc[1][q * 4 + 0]);
                acc[1][q * 4 + 1] = fmaf(f1, w4.y, acc[1][q * 4 + 1]);
                acc[1][q * 4 + 2] = fmaf(f1, w4.z, acc[1][q * 4 + 2]);
                acc[1][q * 4 + 3] = fmaf(f1, w4.w, acc[1][q * 4 + 3]);
            }
        }
    }

#pragma unroll
    for (int me = 0; me < 2; ++me) {
        int node = n0 + te * 2 + me;
        if (node < n) {
#pragma unroll
            for (int q = 0; q < 2; ++q) {
                float4 v = make_float4(acc[me][q * 4 + 0], acc[me][q * 4 + 1],
                                       acc[me][q * 4 + 2], acc[me][q * 4 + 3]);
                *(float4*)(PQ + (size_t)node * KO + col0 + to * 4 + q * 64) = v;
            }
        }
    }
}

// ---------------- segment-max over Q + combine: H[i] = relu(P[i]+b+max_j Q[j]) ----
template<int OUT>
__global__ __launch_bounds__(256, 8)
void segmax_combine(const float* __restrict__ PQ, const int* __restrict__ rowptr,
                    const int* __restrict__ col, const float* __restrict__ bias,
                    float* __restrict__ Hout, int n) {
    constexpr int G = OUT / 4;          // threads per node
    constexpr int NPB = 256 / G;        // nodes per block
    constexpr int KO = 2 * OUT;
    const int gid = threadIdx.x / G;
    const int lane = threadIdx.x % G;
    const int i = blockIdx.x * NPB + gid;
    if (i >= n) return;

    const int r0 = rowptr[i];
    const int r1 = rowptr[i + 1];
    const int c4 = lane * 4;

    float4 m = make_float4(-INFINITY, -INFINITY, -INFINITY, -INFINITY);
    int r = r0;
    for (; r + 1 < r1; r += 2) {
        int s0 = col[r];
        int s1 = col[r + 1];
        const float4 a = *(const float4*)(PQ + (size_t)s0 * KO + OUT + c4);
        const float4 b4 = *(const float4*)(PQ + (size_t)s1 * KO + OUT + c4);
        m.x = fmaxf(m.x, a.x); m.y = fmaxf(m.y, a.y);
        m.z = fmaxf(m.z, a.z); m.w = fmaxf(m.w, a.w);
        m.x = fmaxf(m.x, b4.x); m.y = fmaxf(m.y, b4.y);
        m.z = fmaxf(m.z, b4.z); m.w = fmaxf(m.w, b4.w);
    }
    if (r < r1) {
        int s0 = col[r];
        const float4 a = *(const float4*)(PQ + (size_t)s0 * KO + OUT + c4);
        m.x = fmaxf(m.x, a.x); m.y = fmaxf(m.y, a.y);
        m.z = fmaxf(m.z, a.z); m.w = fmaxf(m.w, a.w);
    }

    const float4 p = *(const float4*)(PQ + (size_t)i * KO + c4);
    const float4 bb = *(const float4*)(bias + c4);
    float4 h;
    h.x = fmaxf(p.x + bb.x + m.x, 0.f);
    h.y = fmaxf(p.y + bb.y + m.y, 0.f);
    h.z = fmaxf(p.z + bb.z + m.z, 0.f);
    h.w = fmaxf(p.w + bb.w + m.w, 0.f);
    *(float4*)(Hout + (size_t)i * OUT + c4) = h;
}

// ---------------- MLP head: out = sigmoid(relu(H @ Wf1 + bf1) @ Wf2 + bf2) ----
__global__ __launch_bounds__(256, 2)
void mlp_head_kernel(const float* __restrict__ H,
                     const float* __restrict__ Wf1,
                     const float* __restrict__ bf1,
                     const float* __restrict__ Wf2,
                     const float* __restrict__ bf2,
                     float* __restrict__ out,
                     int nNodes)
{
    constexpr int K = 256, OUT = 256, BN = 32, BK = 32, ME = 2, NQ = OUT / 64, MO = NQ * 4;
    __shared__ float feat[BN][K + 4];
    __shared__ float wl[BK][OUT];

    const int t  = threadIdx.x;
    const int n0 = blockIdx.x * BN;

    constexpr int C4 = K / 4;
    for (int i = t; i < BN * C4; i += 256) {
        int n = i / C4;
        int c = (i % C4) * 4;
        int nn = min(n0 + n, nNodes - 1);
        *(float4*)(&feat[n][c]) = *(const float4*)(H + (size_t)nn * K + c);
    }

    const int te = t >> 4;
    const int to = t & 15;

    float acc[ME][MO];
#pragma unroll
    for (int me = 0; me < ME; ++me)
#pragma unroll
        for (int mo = 0; mo < MO; ++mo) acc[me][mo] = 0.f;

    for (int kk = 0; kk < K; kk += BK) {
        __syncthreads();
        for (int i = t * 4; i < BK * OUT; i += 1024) {
            *(float4*)(&wl[0][0] + i) = *(const float4*)(Wf1 + (size_t)kk * OUT + i);
        }
        __syncthreads();
#pragma unroll 4
        for (int k = 0; k < BK; ++k) {
            float f[ME];
#pragma unroll
            for (int me = 0; me < ME; ++me) f[me] = feat[te * ME + me][kk + k];
#pragma unroll
            for (int q = 0; q < NQ; ++q) {
                const float4 w4 = *(const float4*)(&wl[k][to * 4 + q * 64]);
#pragma unroll
                for (int me = 0; me < ME; ++me) {
                    acc[me][q * 4 + 0] = fmaf(f[me], w4.x, acc[me][q * 4 + 0]);
                    acc[me][q * 4 + 1] = fmaf(f[me], w4.y, acc[me][q * 4 + 1]);
                    acc[me][q * 4 + 2] = fmaf(f[me], w4.z, acc[me][q * 4 + 2]);
                    acc[me][q * 4 + 3] = fmaf(f[me], w4.w, acc[me][q * 4 + 3]);
                }
            }
        }
    }

    float part[ME] = {0.f, 0.f};
#pragma unroll
    for (int q = 0; q < NQ; ++q) {
#pragma unroll
        for (int r = 0; r < 4; ++r) {
            int o = to * 4 + q * 64 + r;
            float w2 = Wf2[o];
            float bb = bf1[o];
#pragma unroll
            for (int me = 0; me < ME; ++me) {
                float v = fmaxf(acc[me][q * 4 + r] + bb, 0.f);
                part[me] = fmaf(v, w2, part[me]);
            }
        }
    }
#pragma unroll
    for (int s = 8; s >= 1; s >>= 1) {
        part[0] += __shfl_xor(part[0], s, 16);
        part[1] += __shfl_xor(part[1], s, 16);
    }
    if (to == 0) {
#pragma unroll
        for (int me = 0; me < ME; ++me) {
            int n = n0 + te * ME + me;
            if (n < nNodes) {
                float x = part[me] + bf2[0];
                out[n] = 1.f / (1.f + expf(-x));
            }
        }
    }
}

// ---------------- launch ----------------
extern "C" void kernel_launch(void* const* d_in, const int* in_sizes, int n_in,
                              void* d_out, int out_size, void* d_ws, size_t ws_size,
                              hipStream_t stream) {
    const float* X   = (const float*)d_in[0];
    const int*   ei  = (const int*)d_in[1];
    const float* W1  = (const float*)d_in[2];
    const float* b1  = (const float*)d_in[3];
    const float* W2  = (const float*)d_in[4];
    const float* b2  = (const float*)d_in[5];
    const float* W3  = (const float*)d_in[6];
    const float* b3  = (const float*)d_in[7];
    const float* Wf1 = (const float*)d_in[8];
    const float* bf1 = (const float*)d_in[9];
    const float* Wf2 = (const float*)d_in[10];
    const float* bf2 = (const float*)d_in[11];
    float* out = (float*)d_out;

    // edge_index may arrive as int32 (2E elements) or raw int64 (counted as 4E int32)
    int istride = (in_sizes[1] == 4 * NE) ? 2 : 1;
    const int* esrc = ei;
    const int* edst = ei + (size_t)NE * istride;

    // workspace layout (all 16B aligned)
    float* H      = (float*)d_ws;                       // NN*256 f32   (51.2 MB)
    float* PQ     = H + (size_t)NN * 256;               // NN*512 f32   (102.4 MB)
    int*   rowptr = (int*)(PQ + (size_t)NN * 512);      // NN+4 ints
    int*   deg    = rowptr + (NN + 4);                  // NN ints (counts -> cursor)
    int*   col    = deg + NN;                           // NE ints
    float* Wmod   = (float*)(col + NE);                 // up to 128*512 f32

    // ---- CSR build (edge list shared by all three layers) ----
    zeroi_kernel<<<256, 256, 0, stream>>>(deg, NN);
    hist_kernel<<<1024, 256, 0, stream>>>(edst, istride, deg, NE);
    scan_kernel<<<1, 1024, 0, stream>>>(deg, rowptr, NN);
    scatter_kernel<<<1024, 256, 0, stream>>>(esrc, edst, istride, deg, col, NE);

    // ---- layer 1: X[N,16] -> H[N,64] ----
    prepw_kernel<<<(16 * 64 + 255) / 256, 256, 0, stream>>>(W1, Wmod, 16, 64);
    {
        dim3 g((NN + 31) / 32, 1);
        gemm_kernel<16><<<g, 256, 0, stream>>>(X, Wmod, PQ, NN, 128);
    }
    segmax_combine<64><<<(NN + 15) / 16, 256, 0, stream>>>(PQ, rowptr, col, b1, H, NN);

    // ---- layer 2: H[N,64] -> H[N,128] ----
    prepw_kernel<<<(64 * 128 + 255) / 256, 256, 0, stream>>>(W2, Wmod, 64, 128);
    {
        dim3 g((NN + 31) / 32, 2);
        gemm_kernel<64><<<g, 256, 0, stream>>>(H, Wmod, PQ, NN, 256);
    }
    segmax_combine<128><<<(NN + 7) / 8, 256, 0, stream>>>(PQ, rowptr, col, b2, H, NN);

    // ---- layer 3: H[N,128] -> H[N,256] ----
    prepw_kernel<<<(128 * 256 + 255) / 256, 256, 0, stream>>>(W3, Wmod, 128, 256);
    {
        dim3 g((NN + 31) / 32, 4);
        gemm_kernel<128><<<g, 256, 0, stream>>>(H, Wmod, PQ, NN, 512);
    }
    segmax_combine<256><<<(NN + 3) / 4, 256, 0, stream>>>(PQ, rowptr, col, b3, H, NN);

    // ---- MLP head ----
    mlp_head_kernel<<<(NN + 31) / 32, 256, 0, stream>>>(H, Wf1, bf1, Wf2, bf2, out, NN);
}

// Round 3
// 558.863 us; speedup vs baseline: 7.3422x; 1.2815x over previous
//
#include <hip/hip_runtime.h>
#include <math.h>

#define NN 50000
#define NE 800000

typedef unsigned short ushort_t;
typedef __attribute__((ext_vector_type(8))) short bf16x8;
typedef __attribute__((ext_vector_type(4))) float f32x4;

__device__ inline unsigned short f2bf(float f) {
    unsigned int u = __float_as_uint(f);
    u = (u + 0x7fffu + ((u >> 16) & 1u)) >> 16;
    return (unsigned short)u;
}
__device__ inline unsigned int pack2bf(float lo, float hi) {
    return (unsigned int)f2bf(lo) | ((unsigned int)f2bf(hi) << 16);
}

// ---------------- zero int buffer ----------------
__global__ void zeroi_kernel(int* __restrict__ p, int n) {
    int i = blockIdx.x * blockDim.x + threadIdx.x;
    int s = gridDim.x * blockDim.x;
    for (; i < n; i += s) p[i] = 0;
}

// ---------------- CSR build ----------------
__global__ void hist_kernel(const int* __restrict__ edst, int istride,
                            int* __restrict__ deg, int nE) {
    int i = blockIdx.x * blockDim.x + threadIdx.x;
    int s = gridDim.x * blockDim.x;
    for (; i < nE; i += s) atomicAdd(&deg[edst[(size_t)i * istride]], 1);
}

__global__ __launch_bounds__(1024)
void scan_kernel(int* __restrict__ deg, int* __restrict__ rowptr, int n) {
    __shared__ int sums[1024];
    const int t = threadIdx.x;
    const int chunk = (n + 1023) >> 10;
    const int lo = t * chunk;
    const int hi = min(lo + chunk, n);
    int s = 0;
    for (int i = lo; i < hi; ++i) s += deg[i];
    sums[t] = s;
    __syncthreads();
    for (int off = 1; off < 1024; off <<= 1) {
        int v = 0;
        if (t >= off) v = sums[t - off];
        __syncthreads();
        if (t >= off) sums[t] += v;
        __syncthreads();
    }
    int run = sums[t] - s;
    for (int i = lo; i < hi; ++i) {
        int c = deg[i];
        rowptr[i] = run;
        deg[i] = run;
        run += c;
    }
    if (hi == n) rowptr[n] = run;
}

__global__ void scatter_kernel(const int* __restrict__ esrc, const int* __restrict__ edst,
                               int istride, int* __restrict__ cursor,
                               int* __restrict__ col, int nE) {
    int i = blockIdx.x * blockDim.x + threadIdx.x;
    int s = gridDim.x * blockDim.x;
    for (; i < nE; i += s) {
        int d = edst[(size_t)i * istride];
        int pos = atomicAdd(&cursor[d], 1);
        col[pos] = esrc[(size_t)i * istride];
    }
}

// ---------------- weight prep ----------------
// layer1 (f32): Wm[16][128] = [Wa-Wb | Wb]
__global__ void prepw1_kernel(const float* __restrict__ W, float* __restrict__ Wm) {
    int idx = blockIdx.x * blockDim.x + threadIdx.x;
    if (idx >= 16 * 64) return;
    int k = idx / 64, o = idx % 64;
    float wa = W[k * 64 + o];
    float wb = W[(k + 16) * 64 + o];
    Wm[k * 128 + o] = wa - wb;
    Wm[k * 128 + 64 + o] = wb;
}

// conv layers (bf16, transposed): Wt[2*OUT][IN]; row o<OUT: (Wa-Wb)[:,o]; else Wb[:,o-OUT]
__global__ void prepwt_kernel(const float* __restrict__ W, ushort_t* __restrict__ Wt,
                              int IN, int OUT) {
    int idx = blockIdx.x * blockDim.x + threadIdx.x;
    if (idx >= 2 * OUT * IN) return;
    int o = idx / IN, k = idx % IN;
    float v = (o < OUT) ? (W[(size_t)k * OUT + o] - W[(size_t)(k + IN) * OUT + o])
                        : W[(size_t)(k + IN) * OUT + (o - OUT)];
    Wt[idx] = f2bf(v);
}

// head fc1 (bf16, transposed): Wt[n][k] = W[k][n]
__global__ void transw_kernel(const float* __restrict__ W, ushort_t* __restrict__ Wt,
                              int K, int N) {
    int idx = blockIdx.x * blockDim.x + threadIdx.x;
    if (idx >= K * N) return;
    int nn = idx / K, k = idx % K;
    Wt[idx] = f2bf(W[(size_t)k * N + nn]);
}

// ---------------- layer-1 GEMM (f32 vector, K=16) ----------------
__global__ __launch_bounds__(256, 4)
void gemm1_kernel(const float* __restrict__ X, const float* __restrict__ Wm,
                  float* __restrict__ P, ushort_t* __restrict__ Qb, int n) {
    __shared__ float feat[32][20];
    __shared__ float wl[16][128];
    const int t = threadIdx.x;
    const int n0 = blockIdx.x * 32;

    if (t < 128) {
        int e = t >> 2, c = (t & 3) * 4;
        int nn = min(n0 + e, n - 1);
        *(float4*)(&feat[e][c]) = *(const float4*)(X + (size_t)nn * 16 + c);
    }
    {
        int i = t * 4;
        *(float4*)(&wl[0][0] + i) = *(const float4*)(Wm + i);
        i += 1024;
        *(float4*)(&wl[0][0] + i) = *(const float4*)(Wm + i);
    }
    __syncthreads();

    const int te = t >> 4, to = t & 15;
    float acc[2][8];
#pragma unroll
    for (int me = 0; me < 2; ++me)
#pragma unroll
        for (int mo = 0; mo < 8; ++mo) acc[me][mo] = 0.f;

#pragma unroll
    for (int k = 0; k < 16; ++k) {
        float f0 = feat[te * 2 + 0][k];
        float f1 = feat[te * 2 + 1][k];
#pragma unroll
        for (int q = 0; q < 2; ++q) {
            const float4 w4 = *(const float4*)(&wl[k][to * 4 + q * 64]);
            acc[0][q * 4 + 0] = fmaf(f0, w4.x, acc[0][q * 4 + 0]);
            acc[0][q * 4 + 1] = fmaf(f0, w4.y, acc[0][q * 4 + 1]);
            acc[0][q * 4 + 2] = fmaf(f0, w4.z, acc[0][q * 4 + 2]);
            acc[0][q * 4 + 3] = fmaf(f0, w4.w, acc[0][q * 4 + 3]);
            acc[1][q * 4 + 0] = fmaf(f1, w4.x, acc[1][q * 4 + 0]);
            acc[1][q * 4 + 1] = fmaf(f1, w4.y, acc[1][q * 4 + 1]);
            acc[1][q * 4 + 2] = fmaf(f1, w4.z, acc[1][q * 4 + 2]);
            acc[1][q * 4 + 3] = fmaf(f1, w4.w, acc[1][q * 4 + 3]);
        }
    }

#pragma unroll
    for (int me = 0; me < 2; ++me) {
        int node = n0 + te * 2 + me;
        if (node < n) {
            *(float4*)(P + (size_t)node * 64 + to * 4) =
                make_float4(acc[me][0], acc[me][1], acc[me][2], acc[me][3]);
            uint2 qq;
            qq.x = pack2bf(acc[me][4], acc[me][5]);
            qq.y = pack2bf(acc[me][6], acc[me][7]);
            *(uint2*)(Qb + (size_t)node * 64 + to * 4) = qq;
        }
    }
}

// ---------------- MFMA conv GEMM: [P|Q] = A[n,K]bf16 @ Wt^T, split-write ------
// Per wave: 16 rows x (2*OUT) cols; A-frag/B-frag = 8 contiguous K bf16 per lane.
template<int K, int OUT>
__global__ __launch_bounds__(256)
void gemm_mfma(const ushort_t* __restrict__ A, const ushort_t* __restrict__ Wt,
               float* __restrict__ P, ushort_t* __restrict__ Qb, int n) {
    constexpr int NOUT = 2 * OUT;
    constexpr int NF = NOUT / 16;
    constexpr int KB = K / 32;
    const int wave = threadIdx.x >> 6;
    const int lane = threadIdx.x & 63;
    const int row0 = blockIdx.x * 64 + wave * 16;
    const int lr = lane & 15;
    const int kg = lane >> 4;

    f32x4 acc[NF];
#pragma unroll
    for (int i = 0; i < NF; ++i) acc[i] = (f32x4)(0.f);

    int arow = row0 + lr;
    if (arow >= n) arow = n - 1;
    const ushort_t* Aptr = A + (size_t)arow * K + kg * 8;

    for (int kb = 0; kb < KB; ++kb) {
        bf16x8 afrag = *(const bf16x8*)(Aptr + kb * 32);
#pragma unroll
        for (int nf = 0; nf < NF; ++nf) {
            bf16x8 bfrag = *(const bf16x8*)(Wt + (size_t)(nf * 16 + lr) * K + kb * 32 + kg * 8);
            acc[nf] = __builtin_amdgcn_mfma_f32_16x16x32_bf16(afrag, bfrag, acc[nf], 0, 0, 0);
        }
    }

    // D layout: col = lr, row = kg*4 + r
#pragma unroll
    for (int nf = 0; nf < NF; ++nf) {
#pragma unroll
        for (int r = 0; r < 4; ++r) {
            int row = row0 + kg * 4 + r;
            if (row < n) {
                int c = nf * 16 + lr;
                float v = acc[nf][r];
                if (c < OUT) P[(size_t)row * OUT + c] = v;
                else Qb[(size_t)row * OUT + (c - OUT)] = f2bf(v);
            }
        }
    }
}

// ---------------- MFMA head: out = sigmoid(relu(H@Wf1+bf1)@Wf2+bf2) ----------
__global__ __launch_bounds__(256)
void head_mfma(const ushort_t* __restrict__ H, const ushort_t* __restrict__ Wf1t,
               const float* __restrict__ bf1, const float* __restrict__ Wf2,
               const float* __restrict__ bf2, float* __restrict__ out, int n) {
    const int wave = threadIdx.x >> 6;
    const int lane = threadIdx.x & 63;
    const int row0 = blockIdx.x * 64 + wave * 16;
    const int lr = lane & 15;
    const int kg = lane >> 4;

    f32x4 acc[16];
#pragma unroll
    for (int i = 0; i < 16; ++i) acc[i] = (f32x4)(0.f);

    int arow = row0 + lr;
    if (arow >= n) arow = n - 1;
    const ushort_t* Aptr = H + (size_t)arow * 256 + kg * 8;

    for (int kb = 0; kb < 8; ++kb) {
        bf16x8 afrag = *(const bf16x8*)(Aptr + kb * 32);
#pragma unroll
        for (int nf = 0; nf < 16; ++nf) {
            bf16x8 bfrag = *(const bf16x8*)(Wf1t + (size_t)(nf * 16 + lr) * 256 + kb * 32 + kg * 8);
            acc[nf] = __builtin_amdgcn_mfma_f32_16x16x32_bf16(afrag, bfrag, acc[nf], 0, 0, 0);
        }
    }

    // fc2: lane holds rows row0+kg*4+r, cols nf*16+lr
    float part[4] = {0.f, 0.f, 0.f, 0.f};
#pragma unroll
    for (int nf = 0; nf < 16; ++nf) {
        int c = nf * 16 + lr;
        float w2 = Wf2[c];
        float bb = bf1[c];
#pragma unroll
        for (int r = 0; r < 4; ++r)
            part[r] = fmaf(fmaxf(acc[nf][r] + bb, 0.f), w2, part[r]);
    }
#pragma unroll
    for (int s = 1; s < 16; s <<= 1) {
#pragma unroll
        for (int r = 0; r < 4; ++r) part[r] += __shfl_xor(part[r], s, 16);
    }
    if (lr == 0) {
        float b2 = bf2[0];
#pragma unroll
        for (int r = 0; r < 4; ++r) {
            int row = row0 + kg * 4 + r;
            if (row < n) out[row] = 1.f / (1.f + expf(-(part[r] + b2)));
        }
    }
}

// ---------------- segment-max over Qb (bf16) + combine -> H bf16 ----------------
template<int OUT>
__global__ __launch_bounds__(256, 8)
void segmax_combine(const float* __restrict__ P, const ushort_t* __restrict__ Qb,
                    const int* __restrict__ rowptr, const int* __restrict__ col,
                    const float* __restrict__ bias, ushort_t* __restrict__ Hout, int n) {
    constexpr int G = OUT / 8;          // threads per node (8 cols each)
    constexpr int NPB = 256 / G;
    const int gid = threadIdx.x / G;
    const int lane = threadIdx.x % G;
    const int i = blockIdx.x * NPB + gid;
    if (i >= n) return;

    const int r0 = rowptr[i];
    const int r1 = rowptr[i + 1];
    const int c8 = lane * 8;

    float m[8];
#pragma unroll
    for (int j = 0; j < 8; ++j) m[j] = -INFINITY;

    auto domax = [&](uint4 q) {
        m[0] = fmaxf(m[0], __uint_as_float(q.x << 16));
        m[1] = fmaxf(m[1], __uint_as_float(q.x & 0xffff0000u));
        m[2] = fmaxf(m[2], __uint_as_float(q.y << 16));
        m[3] = fmaxf(m[3], __uint_as_float(q.y & 0xffff0000u));
        m[4] = fmaxf(m[4], __uint_as_float(q.z << 16));
        m[5] = fmaxf(m[5], __uint_as_float(q.z & 0xffff0000u));
        m[6] = fmaxf(m[6], __uint_as_float(q.w << 16));
        m[7] = fmaxf(m[7], __uint_as_float(q.w & 0xffff0000u));
    };

    int r = r0;
    for (; r + 1 < r1; r += 2) {
        int s0 = col[r];
        int s1 = col[r + 1];
        uint4 qa = *(const uint4*)(Qb + (size_t)s0 * OUT + c8);
        uint4 qb = *(const uint4*)(Qb + (size_t)s1 * OUT + c8);
        domax(qa);
        domax(qb);
    }
    if (r < r1) {
        int s0 = col[r];
        domax(*(const uint4*)(Qb + (size_t)s0 * OUT + c8));
    }

    const float4 p0 = *(const float4*)(P + (size_t)i * OUT + c8);
    const float4 p1 = *(const float4*)(P + (size_t)i * OUT + c8 + 4);
    const float4 b0 = *(const float4*)(bias + c8);
    const float4 b1 = *(const float4*)(bias + c8 + 4);

    float h[8];
    h[0] = fmaxf(p0.x + b0.x + m[0], 0.f);
    h[1] = fmaxf(p0.y + b0.y + m[1], 0.f);
    h[2] = fmaxf(p0.z + b0.z + m[2], 0.f);
    h[3] = fmaxf(p0.w + b0.w + m[3], 0.f);
    h[4] = fmaxf(p1.x + b1.x + m[4], 0.f);
    h[5] = fmaxf(p1.y + b1.y + m[5], 0.f);
    h[6] = fmaxf(p1.z + b1.z + m[6], 0.f);
    h[7] = fmaxf(p1.w + b1.w + m[7], 0.f);

    uint4 o;
    o.x = pack2bf(h[0], h[1]);
    o.y = pack2bf(h[2], h[3]);
    o.z = pack2bf(h[4], h[5]);
    o.w = pack2bf(h[6], h[7]);
    *(uint4*)(Hout + (size_t)i * OUT + c8) = o;
}

// ---------------- launch ----------------
extern "C" void kernel_launch(void* const* d_in, const int* in_sizes, int n_in,
                              void* d_out, int out_size, void* d_ws, size_t ws_size,
                              hipStream_t stream) {
    const float* X   = (const float*)d_in[0];
    const int*   ei  = (const int*)d_in[1];
    const float* W1  = (const float*)d_in[2];
    const float* b1  = (const float*)d_in[3];
    const float* W2  = (const float*)d_in[4];
    const float* b2  = (const float*)d_in[5];
    const float* W3  = (const float*)d_in[6];
    const float* b3  = (const float*)d_in[7];
    const float* Wf1 = (const float*)d_in[8];
    const float* bf1 = (const float*)d_in[9];
    const float* Wf2 = (const float*)d_in[10];
    const float* bf2 = (const float*)d_in[11];
    float* out = (float*)d_out;

    int istride = (in_sizes[1] == 4 * NE) ? 2 : 1;
    const int* esrc = ei;
    const int* edst = ei + (size_t)NE * istride;

    // workspace layout
    float*    P      = (float*)d_ws;                    // 50000*256 f32
    ushort_t* Qb     = (ushort_t*)(P + (size_t)NN * 256);   // 50000*256 bf16
    ushort_t* Ha     = Qb + (size_t)NN * 256;           // 50000*256 bf16
    ushort_t* Hb     = Ha + (size_t)NN * 256;           // 50000*256 bf16
    int*      rowptr = (int*)(Hb + (size_t)NN * 256);
    int*      deg    = rowptr + (NN + 8);
    int*      col    = deg + NN;
    float*    Wm1    = (float*)(col + NE);              // 16*128 f32
    ushort_t* Wt2    = (ushort_t*)(Wm1 + 2048);         // 256*64
    ushort_t* Wt3    = Wt2 + 256 * 64;                  // 512*128
    ushort_t* Wf1t   = Wt3 + 512 * 128;                 // 256*256

    // ---- CSR build ----
    zeroi_kernel<<<256, 256, 0, stream>>>(deg, NN);
    hist_kernel<<<1024, 256, 0, stream>>>(edst, istride, deg, NE);
    scan_kernel<<<1, 1024, 0, stream>>>(deg, rowptr, NN);
    scatter_kernel<<<1024, 256, 0, stream>>>(esrc, edst, istride, deg, col, NE);

    // ---- weight prep ----
    prepw1_kernel<<<(16 * 64 + 255) / 256, 256, 0, stream>>>(W1, Wm1);
    prepwt_kernel<<<(2 * 128 * 64 + 255) / 256, 256, 0, stream>>>(W2, Wt2, 64, 128);
    prepwt_kernel<<<(2 * 256 * 128 + 255) / 256, 256, 0, stream>>>(W3, Wt3, 128, 256);
    transw_kernel<<<(256 * 256 + 255) / 256, 256, 0, stream>>>(Wf1, Wf1t, 256, 256);

    // ---- layer 1: X -> P[.,64],Qb[.,64] -> Ha bf16[.,64] ----
    gemm1_kernel<<<(NN + 31) / 32, 256, 0, stream>>>(X, Wm1, P, Qb, NN);
    segmax_combine<64><<<(NN * 8 + 255) / 256, 256, 0, stream>>>(P, Qb, rowptr, col, b1, Ha, NN);

    // ---- layer 2: Ha -> P[.,128],Qb[.,128] -> Hb bf16[.,128] ----
    gemm_mfma<64, 128><<<(NN + 63) / 64, 256, 0, stream>>>(Ha, Wt2, P, Qb, NN);
    segmax_combine<128><<<(NN * 16 + 255) / 256, 256, 0, stream>>>(P, Qb, rowptr, col, b2, Hb, NN);

    // ---- layer 3: Hb -> P[.,256],Qb[.,256] -> Ha bf16[.,256] ----
    gemm_mfma<128, 256><<<(NN + 63) / 64, 256, 0, stream>>>(Hb, Wt3, P, Qb, NN);
    segmax_combine<256><<<(NN * 32 + 255) / 256, 256, 0, stream>>>(P, Qb, rowptr, col, b3, Ha, NN);

    // ---- MLP head ----
    head_mfma<<<(NN + 63) / 64, 256, 0, stream>>>(Ha, Wf1t, bf1, Wf2, bf2, out, NN);
}

// Round 4
// 454.659 us; speedup vs baseline: 9.0249x; 1.2292x over previous
//
#include <hip/hip_runtime.h>
#include <math.h>

#define NN 50000
#define NE 800000

typedef unsigned short ushort_t;
typedef __attribute__((ext_vector_type(8))) short bf16x8;
typedef __attribute__((ext_vector_type(4))) float f32x4;

__device__ inline unsigned short f2bf(float f) {
    unsigned int u = __float_as_uint(f);
    u = (u + 0x7fffu + ((u >> 16) & 1u)) >> 16;
    return (unsigned short)u;
}
__device__ inline unsigned int pack2bf(float lo, float hi) {
    return (unsigned int)f2bf(lo) | ((unsigned int)f2bf(hi) << 16);
}

// ---------------- zero int buffer ----------------
__global__ void zeroi_kernel(int* __restrict__ p, int n) {
    int i = blockIdx.x * blockDim.x + threadIdx.x;
    int s = gridDim.x * blockDim.x;
    for (; i < n; i += s) p[i] = 0;
}

// ---------------- CSR build ----------------
__global__ void hist_kernel(const int* __restrict__ edst, int istride,
                            int* __restrict__ deg, int nE) {
    int i = blockIdx.x * blockDim.x + threadIdx.x;
    int s = gridDim.x * blockDim.x;
    for (; i < nE; i += s) atomicAdd(&deg[edst[(size_t)i * istride]], 1);
}

// 3-phase parallel exclusive scan over deg[0..n) -> rowptr[0..n], cursor(deg) rewritten
__global__ __launch_bounds__(256)
void scan_reduce(const int* __restrict__ deg, int* __restrict__ bsum, int n) {
    __shared__ int s[256];
    const int t = threadIdx.x;
    const int i = blockIdx.x * 256 + t;
    s[t] = (i < n) ? deg[i] : 0;
    __syncthreads();
#pragma unroll
    for (int off = 128; off > 0; off >>= 1) {
        if (t < off) s[t] += s[t + off];
        __syncthreads();
    }
    if (t == 0) bsum[blockIdx.x] = s[0];
}

__global__ __launch_bounds__(256)
void scan_tops(const int* __restrict__ bsum, int* __restrict__ boff,
               int* __restrict__ rowptr, int nb, int n) {
    __shared__ int s[256];
    const int t = threadIdx.x;
    const int v = (t < nb) ? bsum[t] : 0;
    s[t] = v;
    __syncthreads();
    for (int off = 1; off < 256; off <<= 1) {
        int u = (t >= off) ? s[t - off] : 0;
        __syncthreads();
        s[t] += u;
        __syncthreads();
    }
    if (t < nb) boff[t] = s[t] - v;          // exclusive block offset
    if (t == 255) rowptr[n] = s[255];        // grand total
}

__global__ __launch_bounds__(256)
void scan_apply(int* __restrict__ deg, const int* __restrict__ boff,
                int* __restrict__ rowptr, int n) {
    __shared__ int s[256];
    const int t = threadIdx.x;
    const int i = blockIdx.x * 256 + t;
    const int v = (i < n) ? deg[i] : 0;
    s[t] = v;
    __syncthreads();
    for (int off = 1; off < 256; off <<= 1) {
        int u = (t >= off) ? s[t - off] : 0;
        __syncthreads();
        s[t] += u;
        __syncthreads();
    }
    if (i < n) {
        int ex = boff[blockIdx.x] + s[t] - v;
        rowptr[i] = ex;
        deg[i] = ex;     // becomes scatter cursor
    }
}

__global__ void scatter_kernel(const int* __restrict__ esrc, const int* __restrict__ edst,
                               int istride, int* __restrict__ cursor,
                               int* __restrict__ col, int nE) {
    int i = blockIdx.x * blockDim.x + threadIdx.x;
    int s = gridDim.x * blockDim.x;
    for (; i < nE; i += s) {
        int d = edst[(size_t)i * istride];
        int pos = atomicAdd(&cursor[d], 1);
        col[pos] = esrc[(size_t)i * istride];
    }
}

// ---------------- weight prep ----------------
// layer1 (f32): Wm[16][128] = [Wa-Wb | Wb]
__global__ void prepw1_kernel(const float* __restrict__ W, float* __restrict__ Wm) {
    int idx = blockIdx.x * blockDim.x + threadIdx.x;
    if (idx >= 16 * 64) return;
    int k = idx / 64, o = idx % 64;
    float wa = W[k * 64 + o];
    float wb = W[(k + 16) * 64 + o];
    Wm[k * 128 + o] = wa - wb;
    Wm[k * 128 + 64 + o] = wb;
}

// conv layers (bf16, transposed): Wt[2*OUT][IN]; row o<OUT: (Wa-Wb)[:,o]; else Wb[:,o-OUT]
__global__ void prepwt_kernel(const float* __restrict__ W, ushort_t* __restrict__ Wt,
                              int IN, int OUT) {
    int idx = blockIdx.x * blockDim.x + threadIdx.x;
    if (idx >= 2 * OUT * IN) return;
    int o = idx / IN, k = idx % IN;
    float v = (o < OUT) ? (W[(size_t)k * OUT + o] - W[(size_t)(k + IN) * OUT + o])
                        : W[(size_t)(k + IN) * OUT + (o - OUT)];
    Wt[idx] = f2bf(v);
}

// head fc1 (bf16, transposed): Wt[n][k] = W[k][n]
__global__ void transw_kernel(const float* __restrict__ W, ushort_t* __restrict__ Wt,
                              int K, int N) {
    int idx = blockIdx.x * blockDim.x + threadIdx.x;
    if (idx >= K * N) return;
    int nn = idx / K, k = idx % K;
    Wt[idx] = f2bf(W[(size_t)k * N + nn]);
}

// ---------------- layer-1 GEMM (f32 vector, K=16) ----------------
__global__ __launch_bounds__(256, 4)
void gemm1_kernel(const float* __restrict__ X, const float* __restrict__ Wm,
                  float* __restrict__ P, ushort_t* __restrict__ Qb, int n) {
    __shared__ float feat[32][20];
    __shared__ float wl[16][128];
    const int t = threadIdx.x;
    const int n0 = blockIdx.x * 32;

    if (t < 128) {
        int e = t >> 2, c = (t & 3) * 4;
        int nn = min(n0 + e, n - 1);
        *(float4*)(&feat[e][c]) = *(const float4*)(X + (size_t)nn * 16 + c);
    }
    {
        int i = t * 4;
        *(float4*)(&wl[0][0] + i) = *(const float4*)(Wm + i);
        i += 1024;
        *(float4*)(&wl[0][0] + i) = *(const float4*)(Wm + i);
    }
    __syncthreads();

    const int te = t >> 4, to = t & 15;
    float acc[2][8];
#pragma unroll
    for (int me = 0; me < 2; ++me)
#pragma unroll
        for (int mo = 0; mo < 8; ++mo) acc[me][mo] = 0.f;

#pragma unroll
    for (int k = 0; k < 16; ++k) {
        float f0 = feat[te * 2 + 0][k];
        float f1 = feat[te * 2 + 1][k];
#pragma unroll
        for (int q = 0; q < 2; ++q) {
            const float4 w4 = *(const float4*)(&wl[k][to * 4 + q * 64]);
            acc[0][q * 4 + 0] = fmaf(f0, w4.x, acc[0][q * 4 + 0]);
            acc[0][q * 4 + 1] = fmaf(f0, w4.y, acc[0][q * 4 + 1]);
            acc[0][q * 4 + 2] = fmaf(f0, w4.z, acc[0][q * 4 + 2]);
            acc[0][q * 4 + 3] = fmaf(f0, w4.w, acc[0][q * 4 + 3]);
            acc[1][q * 4 + 0] = fmaf(f1, w4.x, acc[1][q * 4 + 0]);
            acc[1][q * 4 + 1] = fmaf(f1, w4.y, acc[1][q * 4 + 1]);
            acc[1][q * 4 + 2] = fmaf(f1, w4.z, acc[1][q * 4 + 2]);
            acc[1][q * 4 + 3] = fmaf(f1, w4.w, acc[1][q * 4 + 3]);
        }
    }

#pragma unroll
    for (int me = 0; me < 2; ++me) {
        int node = n0 + te * 2 + me;
        if (node < n) {
            *(float4*)(P + (size_t)node * 64 + to * 4) =
                make_float4(acc[me][0], acc[me][1], acc[me][2], acc[me][3]);
            uint2 qq;
            qq.x = pack2bf(acc[me][4], acc[me][5]);
            qq.y = pack2bf(acc[me][6], acc[me][7]);
            *(uint2*)(Qb + (size_t)node * 64 + to * 4) = qq;
        }
    }
}

// ---------------- MFMA conv GEMM: [P|Q] = A[n,K]bf16 @ Wt^T, split-write ------
template<int K, int OUT>
__global__ __launch_bounds__(256)
void gemm_mfma(const ushort_t* __restrict__ A, const ushort_t* __restrict__ Wt,
               float* __restrict__ P, ushort_t* __restrict__ Qb, int n) {
    constexpr int NOUT = 2 * OUT;
    constexpr int NF = NOUT / 16;
    constexpr int KB = K / 32;
    const int wave = threadIdx.x >> 6;
    const int lane = threadIdx.x & 63;
    const int row0 = blockIdx.x * 64 + wave * 16;
    const int lr = lane & 15;
    const int kg = lane >> 4;

    f32x4 acc[NF];
#pragma unroll
    for (int i = 0; i < NF; ++i) acc[i] = (f32x4)(0.f);

    int arow = row0 + lr;
    if (arow >= n) arow = n - 1;
    const ushort_t* Aptr = A + (size_t)arow * K + kg * 8;

    for (int kb = 0; kb < KB; ++kb) {
        bf16x8 afrag = *(const bf16x8*)(Aptr + kb * 32);
#pragma unroll
        for (int nf = 0; nf < NF; ++nf) {
            bf16x8 bfrag = *(const bf16x8*)(Wt + (size_t)(nf * 16 + lr) * K + kb * 32 + kg * 8);
            acc[nf] = __builtin_amdgcn_mfma_f32_16x16x32_bf16(afrag, bfrag, acc[nf], 0, 0, 0);
        }
    }

    // D layout: col = lr, row = kg*4 + r
#pragma unroll
    for (int nf = 0; nf < NF; ++nf) {
#pragma unroll
        for (int r = 0; r < 4; ++r) {
            int row = row0 + kg * 4 + r;
            if (row < n) {
                int c = nf * 16 + lr;
                float v = acc[nf][r];
                if (c < OUT) P[(size_t)row * OUT + c] = v;
                else Qb[(size_t)row * OUT + (c - OUT)] = f2bf(v);
            }
        }
    }
}

// ---------------- MFMA head: out = sigmoid(relu(H@Wf1+bf1)@Wf2+bf2) ----------
__global__ __launch_bounds__(256)
void head_mfma(const ushort_t* __restrict__ H, const ushort_t* __restrict__ Wf1t,
               const float* __restrict__ bf1, const float* __restrict__ Wf2,
               const float* __restrict__ bf2, float* __restrict__ out, int n) {
    const int wave = threadIdx.x >> 6;
    const int lane = threadIdx.x & 63;
    const int row0 = blockIdx.x * 64 + wave * 16;
    const int lr = lane & 15;
    const int kg = lane >> 4;

    f32x4 acc[16];
#pragma unroll
    for (int i = 0; i < 16; ++i) acc[i] = (f32x4)(0.f);

    int arow = row0 + lr;
    if (arow >= n) arow = n - 1;
    const ushort_t* Aptr = H + (size_t)arow * 256 + kg * 8;

    for (int kb = 0; kb < 8; ++kb) {
        bf16x8 afrag = *(const bf16x8*)(Aptr + kb * 32);
#pragma unroll
        for (int nf = 0; nf < 16; ++nf) {
            bf16x8 bfrag = *(const bf16x8*)(Wf1t + (size_t)(nf * 16 + lr) * 256 + kb * 32 + kg * 8);
            acc[nf] = __builtin_amdgcn_mfma_f32_16x16x32_bf16(afrag, bfrag, acc[nf], 0, 0, 0);
        }
    }

    float part[4] = {0.f, 0.f, 0.f, 0.f};
#pragma unroll
    for (int nf = 0; nf < 16; ++nf) {
        int c = nf * 16 + lr;
        float w2 = Wf2[c];
        float bb = bf1[c];
#pragma unroll
        for (int r = 0; r < 4; ++r)
            part[r] = fmaf(fmaxf(acc[nf][r] + bb, 0.f), w2, part[r]);
    }
#pragma unroll
    for (int s = 1; s < 16; s <<= 1) {
#pragma unroll
        for (int r = 0; r < 4; ++r) part[r] += __shfl_xor(part[r], s, 16);
    }
    if (lr == 0) {
        float b2 = bf2[0];
#pragma unroll
        for (int r = 0; r < 4; ++r) {
            int row = row0 + kg * 4 + r;
            if (row < n) out[row] = 1.f / (1.f + expf(-(part[r] + b2)));
        }
    }
}

// ---------------- segment-max over Qb (bf16) + combine -> H bf16 ----------------
template<int OUT>
__global__ __launch_bounds__(256, 8)
void segmax_combine(const float* __restrict__ P, const ushort_t* __restrict__ Qb,
                    const int* __restrict__ rowptr, const int* __restrict__ col,
                    const float* __restrict__ bias, ushort_t* __restrict__ Hout, int n) {
    constexpr int G = OUT / 8;          // threads per node (8 cols each)
    constexpr int NPB = 256 / G;
    const int gid = threadIdx.x / G;
    const int lane = threadIdx.x % G;
    const int i = blockIdx.x * NPB + gid;
    if (i >= n) return;

    const int r0 = rowptr[i];
    const int r1 = rowptr[i + 1];
    const int c8 = lane * 8;

    float m[8];
#pragma unroll
    for (int j = 0; j < 8; ++j) m[j] = -INFINITY;

    auto domax = [&](uint4 q) {
        m[0] = fmaxf(m[0], __uint_as_float(q.x << 16));
        m[1] = fmaxf(m[1], __uint_as_float(q.x & 0xffff0000u));
        m[2] = fmaxf(m[2], __uint_as_float(q.y << 16));
        m[3] = fmaxf(m[3], __uint_as_float(q.y & 0xffff0000u));
        m[4] = fmaxf(m[4], __uint_as_float(q.z << 16));
        m[5] = fmaxf(m[5], __uint_as_float(q.z & 0xffff0000u));
        m[6] = fmaxf(m[6], __uint_as_float(q.w << 16));
        m[7] = fmaxf(m[7], __uint_as_float(q.w & 0xffff0000u));
    };

    int r = r0;
    for (; r + 1 < r1; r += 2) {
        int s0 = col[r];
        int s1 = col[r + 1];
        uint4 qa = *(const uint4*)(Qb + (size_t)s0 * OUT + c8);
        uint4 qb = *(const uint4*)(Qb + (size_t)s1 * OUT + c8);
        domax(qa);
        domax(qb);
    }
    if (r < r1) {
        int s0 = col[r];
        domax(*(const uint4*)(Qb + (size_t)s0 * OUT + c8));
    }

    const float4 p0 = *(const float4*)(P + (size_t)i * OUT + c8);
    const float4 p1 = *(const float4*)(P + (size_t)i * OUT + c8 + 4);
    const float4 b0 = *(const float4*)(bias + c8);
    const float4 b1 = *(const float4*)(bias + c8 + 4);

    float h[8];
    h[0] = fmaxf(p0.x + b0.x + m[0], 0.f);
    h[1] = fmaxf(p0.y + b0.y + m[1], 0.f);
    h[2] = fmaxf(p0.z + b0.z + m[2], 0.f);
    h[3] = fmaxf(p0.w + b0.w + m[3], 0.f);
    h[4] = fmaxf(p1.x + b1.x + m[4], 0.f);
    h[5] = fmaxf(p1.y + b1.y + m[5], 0.f);
    h[6] = fmaxf(p1.z + b1.z + m[6], 0.f);
    h[7] = fmaxf(p1.w + b1.w + m[7], 0.f);

    uint4 o;
    o.x = pack2bf(h[0], h[1]);
    o.y = pack2bf(h[2], h[3]);
    o.z = pack2bf(h[4], h[5]);
    o.w = pack2bf(h[6], h[7]);
    *(uint4*)(Hout + (size_t)i * OUT + c8) = o;
}

// ---------------- launch ----------------
extern "C" void kernel_launch(void* const* d_in, const int* in_sizes, int n_in,
                              void* d_out, int out_size, void* d_ws, size_t ws_size,
                              hipStream_t stream) {
    const float* X   = (const float*)d_in[0];
    const int*   ei  = (const int*)d_in[1];
    const float* W1  = (const float*)d_in[2];
    const float* b1  = (const float*)d_in[3];
    const float* W2  = (const float*)d_in[4];
    const float* b2  = (const float*)d_in[5];
    const float* W3  = (const float*)d_in[6];
    const float* b3  = (const float*)d_in[7];
    const float* Wf1 = (const float*)d_in[8];
    const float* bf1 = (const float*)d_in[9];
    const float* Wf2 = (const float*)d_in[10];
    const float* bf2 = (const float*)d_in[11];
    float* out = (float*)d_out;

    int istride = (in_sizes[1] == 4 * NE) ? 2 : 1;
    const int* esrc = ei;
    const int* edst = ei + (size_t)NE * istride;

    // workspace layout
    float*    P      = (float*)d_ws;                        // 50000*256 f32
    ushort_t* Qb     = (ushort_t*)(P + (size_t)NN * 256);   // 50000*256 bf16
    ushort_t* Ha     = Qb + (size_t)NN * 256;               // 50000*256 bf16
    ushort_t* Hb     = Ha + (size_t)NN * 256;               // 50000*256 bf16
    int*      rowptr = (int*)(Hb + (size_t)NN * 256);
    int*      deg    = rowptr + (NN + 8);
    int*      col    = deg + NN;
    int*      bsum   = col + NE;                            // 256 ints
    int*      boff   = bsum + 256;                          // 256 ints
    float*    Wm1    = (float*)(boff + 256);                // 16*128 f32
    ushort_t* Wt2    = (ushort_t*)(Wm1 + 2048);             // 256*64
    ushort_t* Wt3    = Wt2 + 256 * 64;                      // 512*128
    ushort_t* Wf1t   = Wt3 + 512 * 128;                     // 256*256

    const int NB = (NN + 255) / 256;   // 196 scan blocks

    // ---- CSR build ----
    zeroi_kernel<<<256, 256, 0, stream>>>(deg, NN);
    hist_kernel<<<1024, 256, 0, stream>>>(edst, istride, deg, NE);
    scan_reduce<<<NB, 256, 0, stream>>>(deg, bsum, NN);
    scan_tops<<<1, 256, 0, stream>>>(bsum, boff, rowptr, NB, NN);
    scan_apply<<<NB, 256, 0, stream>>>(deg, boff, rowptr, NN);
    scatter_kernel<<<1024, 256, 0, stream>>>(esrc, edst, istride, deg, col, NE);

    // ---- weight prep ----
    prepw1_kernel<<<(16 * 64 + 255) / 256, 256, 0, stream>>>(W1, Wm1);
    prepwt_kernel<<<(2 * 128 * 64 + 255) / 256, 256, 0, stream>>>(W2, Wt2, 64, 128);
    prepwt_kernel<<<(2 * 256 * 128 + 255) / 256, 256, 0, stream>>>(W3, Wt3, 128, 256);
    transw_kernel<<<(256 * 256 + 255) / 256, 256, 0, stream>>>(Wf1, Wf1t, 256, 256);

    // ---- layer 1: X -> P[.,64],Qb[.,64] -> Ha bf16[.,64] ----
    gemm1_kernel<<<(NN + 31) / 32, 256, 0, stream>>>(X, Wm1, P, Qb, NN);
    segmax_combine<64><<<(NN * 8 + 255) / 256, 256, 0, stream>>>(P, Qb, rowptr, col, b1, Ha, NN);

    // ---- layer 2: Ha -> P[.,128],Qb[.,128] -> Hb bf16[.,128] ----
    gemm_mfma<64, 128><<<(NN + 63) / 64, 256, 0, stream>>>(Ha, Wt2, P, Qb, NN);
    segmax_combine<128><<<(NN * 16 + 255) / 256, 256, 0, stream>>>(P, Qb, rowptr, col, b2, Hb, NN);

    // ---- layer 3: Hb -> P[.,256],Qb[.,256] -> Ha bf16[.,256] ----
    gemm_mfma<128, 256><<<(NN + 63) / 64, 256, 0, stream>>>(Hb, Wt3, P, Qb, NN);
    segmax_combine<256><<<(NN * 32 + 255) / 256, 256, 0, stream>>>(P, Qb, rowptr, col, b3, Ha, NN);

    // ---- MLP head ----
    head_mfma<<<(NN + 63) / 64, 256, 0, stream>>>(Ha, Wf1t, bf1, Wf2, bf2, out, NN);
}

// Round 5
// 423.651 us; speedup vs baseline: 9.6855x; 1.0732x over previous
//
#include <hip/hip_runtime.h>
#include <math.h>

#define NN 50000
#define NE 800000

typedef unsigned short ushort_t;
typedef __attribute__((ext_vector_type(8))) short bf16x8;
typedef __attribute__((ext_vector_type(4))) float f32x4;

__device__ inline unsigned short f2bf(float f) {
    unsigned int u = __float_as_uint(f);
    u = (u + 0x7fffu + ((u >> 16) & 1u)) >> 16;
    return (unsigned short)u;
}
__device__ inline unsigned int pack2bf(float lo, float hi) {
    return (unsigned int)f2bf(lo) | ((unsigned int)f2bf(hi) << 16);
}

// ---------------- zero int buffer ----------------
__global__ void zeroi_kernel(int* __restrict__ p, int n) {
    int i = blockIdx.x * blockDim.x + threadIdx.x;
    int s = gridDim.x * blockDim.x;
    for (; i < n; i += s) p[i] = 0;
}

// ---------------- CSR build ----------------
__global__ void hist_kernel(const int* __restrict__ edst, int istride,
                            int* __restrict__ deg, int nE) {
    int i = blockIdx.x * blockDim.x + threadIdx.x;
    int s = gridDim.x * blockDim.x;
    for (; i < nE; i += s) atomicAdd(&deg[edst[(size_t)i * istride]], 1);
}

__global__ __launch_bounds__(256)
void scan_reduce(const int* __restrict__ deg, int* __restrict__ bsum, int n) {
    __shared__ int s[256];
    const int t = threadIdx.x;
    const int i = blockIdx.x * 256 + t;
    s[t] = (i < n) ? deg[i] : 0;
    __syncthreads();
#pragma unroll
    for (int off = 128; off > 0; off >>= 1) {
        if (t < off) s[t] += s[t + off];
        __syncthreads();
    }
    if (t == 0) bsum[blockIdx.x] = s[0];
}

__global__ __launch_bounds__(256)
void scan_tops(const int* __restrict__ bsum, int* __restrict__ boff,
               int* __restrict__ rowptr, int nb, int n) {
    __shared__ int s[256];
    const int t = threadIdx.x;
    const int v = (t < nb) ? bsum[t] : 0;
    s[t] = v;
    __syncthreads();
    for (int off = 1; off < 256; off <<= 1) {
        int u = (t >= off) ? s[t - off] : 0;
        __syncthreads();
        s[t] += u;
        __syncthreads();
    }
    if (t < nb) boff[t] = s[t] - v;
    if (t == 255) rowptr[n] = s[255];
}

__global__ __launch_bounds__(256)
void scan_apply(int* __restrict__ deg, const int* __restrict__ boff,
                int* __restrict__ rowptr, int n) {
    __shared__ int s[256];
    const int t = threadIdx.x;
    const int i = blockIdx.x * 256 + t;
    const int v = (i < n) ? deg[i] : 0;
    s[t] = v;
    __syncthreads();
    for (int off = 1; off < 256; off <<= 1) {
        int u = (t >= off) ? s[t - off] : 0;
        __syncthreads();
        s[t] += u;
        __syncthreads();
    }
    if (i < n) {
        int ex = boff[blockIdx.x] + s[t] - v;
        rowptr[i] = ex;
        deg[i] = ex;
    }
}

__global__ void scatter_kernel(const int* __restrict__ esrc, const int* __restrict__ edst,
                               int istride, int* __restrict__ cursor,
                               int* __restrict__ col, int nE) {
    int i = blockIdx.x * blockDim.x + threadIdx.x;
    int s = gridDim.x * blockDim.x;
    for (; i < nE; i += s) {
        int d = edst[(size_t)i * istride];
        int pos = atomicAdd(&cursor[d], 1);
        col[pos] = esrc[(size_t)i * istride];
    }
}

// ---------------- weight prep ----------------
__global__ void prepw1_kernel(const float* __restrict__ W, float* __restrict__ Wm) {
    int idx = blockIdx.x * blockDim.x + threadIdx.x;
    if (idx >= 16 * 64) return;
    int k = idx / 64, o = idx % 64;
    float wa = W[k * 64 + o];
    float wb = W[(k + 16) * 64 + o];
    Wm[k * 128 + o] = wa - wb;
    Wm[k * 128 + 64 + o] = wb;
}

__global__ void prepwt_kernel(const float* __restrict__ W, ushort_t* __restrict__ Wt,
                              int IN, int OUT) {
    int idx = blockIdx.x * blockDim.x + threadIdx.x;
    if (idx >= 2 * OUT * IN) return;
    int o = idx / IN, k = idx % IN;
    float v = (o < OUT) ? (W[(size_t)k * OUT + o] - W[(size_t)(k + IN) * OUT + o])
                        : W[(size_t)(k + IN) * OUT + (o - OUT)];
    Wt[idx] = f2bf(v);
}

__global__ void transw_kernel(const float* __restrict__ W, ushort_t* __restrict__ Wt,
                              int K, int N) {
    int idx = blockIdx.x * blockDim.x + threadIdx.x;
    if (idx >= K * N) return;
    int nn = idx / K, k = idx % K;
    Wt[idx] = f2bf(W[(size_t)k * N + nn]);
}

// ---------------- layer-1 GEMM (f32 vector, K=16) ----------------
__global__ __launch_bounds__(256, 4)
void gemm1_kernel(const float* __restrict__ X, const float* __restrict__ Wm,
                  float* __restrict__ P, ushort_t* __restrict__ Qb, int n) {
    __shared__ float feat[32][20];
    __shared__ float wl[16][128];
    const int t = threadIdx.x;
    const int n0 = blockIdx.x * 32;

    if (t < 128) {
        int e = t >> 2, c = (t & 3) * 4;
        int nn = min(n0 + e, n - 1);
        *(float4*)(&feat[e][c]) = *(const float4*)(X + (size_t)nn * 16 + c);
    }
    {
        int i = t * 4;
        *(float4*)(&wl[0][0] + i) = *(const float4*)(Wm + i);
        i += 1024;
        *(float4*)(&wl[0][0] + i) = *(const float4*)(Wm + i);
    }
    __syncthreads();

    const int te = t >> 4, to = t & 15;
    float acc[2][8];
#pragma unroll
    for (int me = 0; me < 2; ++me)
#pragma unroll
        for (int mo = 0; mo < 8; ++mo) acc[me][mo] = 0.f;

#pragma unroll
    for (int k = 0; k < 16; ++k) {
        float f0 = feat[te * 2 + 0][k];
        float f1 = feat[te * 2 + 1][k];
#pragma unroll
        for (int q = 0; q < 2; ++q) {
            const float4 w4 = *(const float4*)(&wl[k][to * 4 + q * 64]);
            acc[0][q * 4 + 0] = fmaf(f0, w4.x, acc[0][q * 4 + 0]);
            acc[0][q * 4 + 1] = fmaf(f0, w4.y, acc[0][q * 4 + 1]);
            acc[0][q * 4 + 2] = fmaf(f0, w4.z, acc[0][q * 4 + 2]);
            acc[0][q * 4 + 3] = fmaf(f0, w4.w, acc[0][q * 4 + 3]);
            acc[1][q * 4 + 0] = fmaf(f1, w4.x, acc[1][q * 4 + 0]);
            acc[1][q * 4 + 1] = fmaf(f1, w4.y, acc[1][q * 4 + 1]);
            acc[1][q * 4 + 2] = fmaf(f1, w4.z, acc[1][q * 4 + 2]);
            acc[1][q * 4 + 3] = fmaf(f1, w4.w, acc[1][q * 4 + 3]);
        }
    }

#pragma unroll
    for (int me = 0; me < 2; ++me) {
        int node = n0 + te * 2 + me;
        if (node < n) {
            *(float4*)(P + (size_t)node * 64 + to * 4) =
                make_float4(acc[me][0], acc[me][1], acc[me][2], acc[me][3]);
            uint2 qq;
            qq.x = pack2bf(acc[me][4], acc[me][5]);
            qq.y = pack2bf(acc[me][6], acc[me][7]);
            *(uint2*)(Qb + (size_t)node * 64 + to * 4) = qq;
        }
    }
}

// ---------------- MFMA conv GEMM, latency-tiled ----------------
// Block: 4 waves x (MR*16) rows; cols: blockIdx.y * (NF*16). Per kb-step each
// wave batch-loads MR A-frags + NF B-frags (registers), then MR*NF MFMAs.
template<int K, int OUT, int NF, int MR>
__global__ __launch_bounds__(256)
void gemm_mfma(const ushort_t* __restrict__ A, const ushort_t* __restrict__ Wt,
               float* __restrict__ P, ushort_t* __restrict__ Qb, int n) {
    constexpr int KB = K / 32;
    const int wave = threadIdx.x >> 6;
    const int lane = threadIdx.x & 63;
    const int lr = lane & 15;
    const int kg = lane >> 4;
    const int row0 = (blockIdx.x * 4 + wave) * (MR * 16);
    const int col0 = blockIdx.y * (NF * 16);

    f32x4 acc[MR][NF];
#pragma unroll
    for (int m = 0; m < MR; ++m)
#pragma unroll
        for (int f = 0; f < NF; ++f) acc[m][f] = (f32x4)(0.f);

    const ushort_t* Ap[MR];
#pragma unroll
    for (int m = 0; m < MR; ++m) {
        int arow = row0 + m * 16 + lr;
        if (arow >= n) arow = n - 1;
        Ap[m] = A + (size_t)arow * K + kg * 8;
    }
    const ushort_t* Bp = Wt + (size_t)(col0 + lr) * K + kg * 8;

#pragma unroll
    for (int kb = 0; kb < KB; ++kb) {
        bf16x8 af[MR];
#pragma unroll
        for (int m = 0; m < MR; ++m) af[m] = *(const bf16x8*)(Ap[m] + kb * 32);
        bf16x8 bfv[NF];
#pragma unroll
        for (int f = 0; f < NF; ++f)
            bfv[f] = *(const bf16x8*)(Bp + (size_t)f * 16 * K + kb * 32);
#pragma unroll
        for (int f = 0; f < NF; ++f)
#pragma unroll
            for (int m = 0; m < MR; ++m)
                acc[m][f] = __builtin_amdgcn_mfma_f32_16x16x32_bf16(af[m], bfv[f], acc[m][f], 0, 0, 0);
    }

    // D layout: col = lr, row = kg*4 + r
#pragma unroll
    for (int m = 0; m < MR; ++m) {
#pragma unroll
        for (int f = 0; f < NF; ++f) {
#pragma unroll
            for (int r = 0; r < 4; ++r) {
                int row = row0 + m * 16 + kg * 4 + r;
                if (row < n) {
                    int c = col0 + f * 16 + lr;
                    float v = acc[m][f][r];
                    if (c < OUT) P[(size_t)row * OUT + c] = v;
                    else Qb[(size_t)row * OUT + (c - OUT)] = f2bf(v);
                }
            }
        }
    }
}

// ---------------- MFMA head: out = sigmoid(relu(H@Wf1+bf1)@Wf2+bf2) ----------
__global__ __launch_bounds__(256)
void head_mfma(const ushort_t* __restrict__ H, const ushort_t* __restrict__ Wf1t,
               const float* __restrict__ bf1, const float* __restrict__ Wf2,
               const float* __restrict__ bf2, float* __restrict__ out, int n) {
    const int wave = threadIdx.x >> 6;
    const int lane = threadIdx.x & 63;
    const int row0 = blockIdx.x * 64 + wave * 16;
    const int lr = lane & 15;
    const int kg = lane >> 4;

    f32x4 acc[16];
#pragma unroll
    for (int i = 0; i < 16; ++i) acc[i] = (f32x4)(0.f);

    int arow = row0 + lr;
    if (arow >= n) arow = n - 1;
    const ushort_t* Aptr = H + (size_t)arow * 256 + kg * 8;
    const ushort_t* Bp = Wf1t + (size_t)lr * 256 + kg * 8;

#pragma unroll
    for (int kb = 0; kb < 8; ++kb) {
        bf16x8 afrag = *(const bf16x8*)(Aptr + kb * 32);
        bf16x8 bfv[16];
#pragma unroll
        for (int nf = 0; nf < 16; ++nf)
            bfv[nf] = *(const bf16x8*)(Bp + (size_t)nf * 16 * 256 + kb * 32);
#pragma unroll
        for (int nf = 0; nf < 16; ++nf)
            acc[nf] = __builtin_amdgcn_mfma_f32_16x16x32_bf16(afrag, bfv[nf], acc[nf], 0, 0, 0);
    }

    float part[4] = {0.f, 0.f, 0.f, 0.f};
#pragma unroll
    for (int nf = 0; nf < 16; ++nf) {
        int c = nf * 16 + lr;
        float w2 = Wf2[c];
        float bb = bf1[c];
#pragma unroll
        for (int r = 0; r < 4; ++r)
            part[r] = fmaf(fmaxf(acc[nf][r] + bb, 0.f), w2, part[r]);
    }
#pragma unroll
    for (int s = 1; s < 16; s <<= 1) {
#pragma unroll
        for (int r = 0; r < 4; ++r) part[r] += __shfl_xor(part[r], s, 16);
    }
    if (lr == 0) {
        float b2 = bf2[0];
#pragma unroll
        for (int r = 0; r < 4; ++r) {
            int row = row0 + kg * 4 + r;
            if (row < n) out[row] = 1.f / (1.f + expf(-(part[r] + b2)));
        }
    }
}

// ---------------- segment-max over Qb (bf16) + combine -> H bf16 ----------------
template<int OUT>
__global__ __launch_bounds__(256, 8)
void segmax_combine(const float* __restrict__ P, const ushort_t* __restrict__ Qb,
                    const int* __restrict__ rowptr, const int* __restrict__ col,
                    const float* __restrict__ bias, ushort_t* __restrict__ Hout, int n) {
    constexpr int G = OUT / 8;
    constexpr int NPB = 256 / G;
    const int gid = threadIdx.x / G;
    const int lane = threadIdx.x % G;
    const int i = blockIdx.x * NPB + gid;
    if (i >= n) return;

    const int r0 = rowptr[i];
    const int r1 = rowptr[i + 1];
    const int c8 = lane * 8;

    float m[8];
#pragma unroll
    for (int j = 0; j < 8; ++j) m[j] = -INFINITY;

    auto domax = [&](uint4 q) {
        m[0] = fmaxf(m[0], __uint_as_float(q.x << 16));
        m[1] = fmaxf(m[1], __uint_as_float(q.x & 0xffff0000u));
        m[2] = fmaxf(m[2], __uint_as_float(q.y << 16));
        m[3] = fmaxf(m[3], __uint_as_float(q.y & 0xffff0000u));
        m[4] = fmaxf(m[4], __uint_as_float(q.z << 16));
        m[5] = fmaxf(m[5], __uint_as_float(q.z & 0xffff0000u));
        m[6] = fmaxf(m[6], __uint_as_float(q.w << 16));
        m[7] = fmaxf(m[7], __uint_as_float(q.w & 0xffff0000u));
    };

    int r = r0;
    for (; r + 1 < r1; r += 2) {
        int s0 = col[r];
        int s1 = col[r + 1];
        uint4 qa = *(const uint4*)(Qb + (size_t)s0 * OUT + c8);
        uint4 qb = *(const uint4*)(Qb + (size_t)s1 * OUT + c8);
        domax(qa);
        domax(qb);
    }
    if (r < r1) {
        int s0 = col[r];
        domax(*(const uint4*)(Qb + (size_t)s0 * OUT + c8));
    }

    const float4 p0 = *(const float4*)(P + (size_t)i * OUT + c8);
    const float4 p1 = *(const float4*)(P + (size_t)i * OUT + c8 + 4);
    const float4 b0 = *(const float4*)(bias + c8);
    const float4 b1 = *(const float4*)(bias + c8 + 4);

    float h[8];
    h[0] = fmaxf(p0.x + b0.x + m[0], 0.f);
    h[1] = fmaxf(p0.y + b0.y + m[1], 0.f);
    h[2] = fmaxf(p0.z + b0.z + m[2], 0.f);
    h[3] = fmaxf(p0.w + b0.w + m[3], 0.f);
    h[4] = fmaxf(p1.x + b1.x + m[4], 0.f);
    h[5] = fmaxf(p1.y + b1.y + m[5], 0.f);
    h[6] = fmaxf(p1.z + b1.z + m[6], 0.f);
    h[7] = fmaxf(p1.w + b1.w + m[7], 0.f);

    uint4 o;
    o.x = pack2bf(h[0], h[1]);
    o.y = pack2bf(h[2], h[3]);
    o.z = pack2bf(h[4], h[5]);
    o.w = pack2bf(h[6], h[7]);
    *(uint4*)(Hout + (size_t)i * OUT + c8) = o;
}

// ---------------- launch ----------------
extern "C" void kernel_launch(void* const* d_in, const int* in_sizes, int n_in,
                              void* d_out, int out_size, void* d_ws, size_t ws_size,
                              hipStream_t stream) {
    const float* X   = (const float*)d_in[0];
    const int*   ei  = (const int*)d_in[1];
    const float* W1  = (const float*)d_in[2];
    const float* b1  = (const float*)d_in[3];
    const float* W2  = (const float*)d_in[4];
    const float* b2  = (const float*)d_in[5];
    const float* W3  = (const float*)d_in[6];
    const float* b3  = (const float*)d_in[7];
    const float* Wf1 = (const float*)d_in[8];
    const float* bf1 = (const float*)d_in[9];
    const float* Wf2 = (const float*)d_in[10];
    const float* bf2 = (const float*)d_in[11];
    float* out = (float*)d_out;

    int istride = (in_sizes[1] == 4 * NE) ? 2 : 1;
    const int* esrc = ei;
    const int* edst = ei + (size_t)NE * istride;

    // workspace layout
    float*    P      = (float*)d_ws;                        // 50000*256 f32
    ushort_t* Qb     = (ushort_t*)(P + (size_t)NN * 256);   // 50000*256 bf16
    ushort_t* Ha     = Qb + (size_t)NN * 256;               // 50000*256 bf16
    ushort_t* Hb     = Ha + (size_t)NN * 256;               // 50000*256 bf16
    int*      rowptr = (int*)(Hb + (size_t)NN * 256);
    int*      deg    = rowptr + (NN + 8);
    int*      col    = deg + NN;
    int*      bsum   = col + NE;
    int*      boff   = bsum + 256;
    float*    Wm1    = (float*)(boff + 256);
    ushort_t* Wt2    = (ushort_t*)(Wm1 + 2048);
    ushort_t* Wt3    = Wt2 + 256 * 64;
    ushort_t* Wf1t   = Wt3 + 512 * 128;

    const int NB = (NN + 255) / 256;

    // ---- CSR build ----
    zeroi_kernel<<<256, 256, 0, stream>>>(deg, NN);
    hist_kernel<<<1024, 256, 0, stream>>>(edst, istride, deg, NE);
    scan_reduce<<<NB, 256, 0, stream>>>(deg, bsum, NN);
    scan_tops<<<1, 256, 0, stream>>>(bsum, boff, rowptr, NB, NN);
    scan_apply<<<NB, 256, 0, stream>>>(deg, boff, rowptr, NN);
    scatter_kernel<<<1024, 256, 0, stream>>>(esrc, edst, istride, deg, col, NE);

    // ---- weight prep ----
    prepw1_kernel<<<(16 * 64 + 255) / 256, 256, 0, stream>>>(W1, Wm1);
    prepwt_kernel<<<(2 * 128 * 64 + 255) / 256, 256, 0, stream>>>(W2, Wt2, 64, 128);
    prepwt_kernel<<<(2 * 256 * 128 + 255) / 256, 256, 0, stream>>>(W3, Wt3, 128, 256);
    transw_kernel<<<(256 * 256 + 255) / 256, 256, 0, stream>>>(Wf1, Wf1t, 256, 256);

    const int GB = (NN + 127) / 128;   // row blocks for gemm_mfma (128 rows/block)

    // ---- layer 1: X -> P[.,64],Qb[.,64] -> Ha bf16[.,64] ----
    gemm1_kernel<<<(NN + 31) / 32, 256, 0, stream>>>(X, Wm1, P, Qb, NN);
    segmax_combine<64><<<(NN * 8 + 255) / 256, 256, 0, stream>>>(P, Qb, rowptr, col, b1, Ha, NN);

    // ---- layer 2: Ha -> P[.,128],Qb[.,128] -> Hb bf16[.,128] ----
    {
        dim3 g(GB, 2);
        gemm_mfma<64, 128, 8, 2><<<g, 256, 0, stream>>>(Ha, Wt2, P, Qb, NN);
    }
    segmax_combine<128><<<(NN * 16 + 255) / 256, 256, 0, stream>>>(P, Qb, rowptr, col, b2, Hb, NN);

    // ---- layer 3: Hb -> P[.,256],Qb[.,256] -> Ha bf16[.,256] ----
    {
        dim3 g(GB, 4);
        gemm_mfma<128, 256, 8, 2><<<g, 256, 0, stream>>>(Hb, Wt3, P, Qb, NN);
    }
    segmax_combine<256><<<(NN * 32 + 255) / 256, 256, 0, stream>>>(P, Qb, rowptr, col, b3, Ha, NN);

    // ---- MLP head ----
    head_mfma<<<(NN + 63) / 64, 256, 0, stream>>>(Ha, Wf1t, bf1, Wf2, bf2, out, NN);
}

// Round 6
// 367.683 us; speedup vs baseline: 11.1598x; 1.1522x over previous
//
#include <hip/hip_runtime.h>
#include <math.h>

#define NN 50000
#define NE 800000

typedef unsigned short ushort_t;
typedef __attribute__((ext_vector_type(8))) short bf16x8;
typedef __attribute__((ext_vector_type(4))) float f32x4;

__device__ inline unsigned short f2bf(float f) {
    unsigned int u = __float_as_uint(f);
    u = (u + 0x7fffu + ((u >> 16) & 1u)) >> 16;
    return (unsigned short)u;
}
__device__ inline unsigned int pack2bf(float lo, float hi) {
    return (unsigned int)f2bf(lo) | ((unsigned int)f2bf(hi) << 16);
}

// ---------------- zero buffers ----------------
__global__ void zeroi_kernel(int* __restrict__ p, int n) {
    int i = blockIdx.x * blockDim.x + threadIdx.x;
    int s = gridDim.x * blockDim.x;
    for (; i < n; i += s) p[i] = 0;
}

// ---------------- CSR build ----------------
__global__ void hist_kernel(const int* __restrict__ edst, int istride,
                            int* __restrict__ deg, int nE) {
    int i = blockIdx.x * blockDim.x + threadIdx.x;
    int s = gridDim.x * blockDim.x;
    for (; i < nE; i += s) atomicAdd(&deg[edst[(size_t)i * istride]], 1);
}

__global__ __launch_bounds__(256)
void scan_reduce(const int* __restrict__ deg, int* __restrict__ bsum, int n) {
    __shared__ int s[256];
    const int t = threadIdx.x;
    const int i = blockIdx.x * 256 + t;
    s[t] = (i < n) ? deg[i] : 0;
    __syncthreads();
#pragma unroll
    for (int off = 128; off > 0; off >>= 1) {
        if (t < off) s[t] += s[t + off];
        __syncthreads();
    }
    if (t == 0) bsum[blockIdx.x] = s[0];
}

__global__ __launch_bounds__(256)
void scan_tops(const int* __restrict__ bsum, int* __restrict__ boff,
               int* __restrict__ rowptr, int nb, int n) {
    __shared__ int s[256];
    const int t = threadIdx.x;
    const int v = (t < nb) ? bsum[t] : 0;
    s[t] = v;
    __syncthreads();
    for (int off = 1; off < 256; off <<= 1) {
        int u = (t >= off) ? s[t - off] : 0;
        __syncthreads();
        s[t] += u;
        __syncthreads();
    }
    if (t < nb) boff[t] = s[t] - v;
    if (t == 255) rowptr[n] = s[255];
}

__global__ __launch_bounds__(256)
void scan_apply(int* __restrict__ deg, const int* __restrict__ boff,
                int* __restrict__ rowptr, int n) {
    __shared__ int s[256];
    const int t = threadIdx.x;
    const int i = blockIdx.x * 256 + t;
    const int v = (i < n) ? deg[i] : 0;
    s[t] = v;
    __syncthreads();
    for (int off = 1; off < 256; off <<= 1) {
        int u = (t >= off) ? s[t - off] : 0;
        __syncthreads();
        s[t] += u;
        __syncthreads();
    }
    if (i < n) {
        int ex = boff[blockIdx.x] + s[t] - v;
        rowptr[i] = ex;
        deg[i] = ex;
    }
}

__global__ void scatter_kernel(const int* __restrict__ esrc, const int* __restrict__ edst,
                               int istride, int* __restrict__ cursor,
                               int* __restrict__ col, int nE) {
    int i = blockIdx.x * blockDim.x + threadIdx.x;
    int s = gridDim.x * blockDim.x;
    for (; i < nE; i += s) {
        int d = edst[(size_t)i * istride];
        int pos = atomicAdd(&cursor[d], 1);
        col[pos] = esrc[(size_t)i * istride];
    }
}

// ---------------- weight / input prep ----------------
// layer-1 weights, transposed+padded: Wt1[128][32]; k>=16 zero
__global__ void prepwt1_kernel(const float* __restrict__ W, ushort_t* __restrict__ Wt) {
    int idx = blockIdx.x * blockDim.x + threadIdx.x;
    if (idx >= 128 * 32) return;
    int o = idx / 32, k = idx % 32;
    float v = 0.f;
    if (k < 16)
        v = (o < 64) ? (W[k * 64 + o] - W[(k + 16) * 64 + o])
                     : W[(k + 16) * 64 + (o - 64)];
    Wt[idx] = f2bf(v);
}

// X f32[NN][16] -> Xb bf16[NN][32] zero-padded
__global__ void xpad_kernel(const float* __restrict__ X, ushort_t* __restrict__ Xb, int n) {
    int idx = blockIdx.x * blockDim.x + threadIdx.x;
    int s = gridDim.x * blockDim.x;
    for (; idx < n * 32; idx += s) {
        int row = idx >> 5, c = idx & 31;
        Xb[idx] = (c < 16) ? f2bf(X[(size_t)row * 16 + c]) : (ushort_t)0;
    }
}

// conv layers (bf16, transposed): Wt[2*OUT][IN]
__global__ void prepwt_kernel(const float* __restrict__ W, ushort_t* __restrict__ Wt,
                              int IN, int OUT) {
    int idx = blockIdx.x * blockDim.x + threadIdx.x;
    if (idx >= 2 * OUT * IN) return;
    int o = idx / IN, k = idx % IN;
    float v = (o < OUT) ? (W[(size_t)k * OUT + o] - W[(size_t)(k + IN) * OUT + o])
                        : W[(size_t)(k + IN) * OUT + (o - OUT)];
    Wt[idx] = f2bf(v);
}

// head fc1 (bf16, transposed): Wt[n][k] = W[k][n]
__global__ void transw_kernel(const float* __restrict__ W, ushort_t* __restrict__ Wt,
                              int K, int N) {
    int idx = blockIdx.x * blockDim.x + threadIdx.x;
    if (idx >= K * N) return;
    int nn = idx / K, k = idx % K;
    Wt[idx] = f2bf(W[(size_t)k * N + nn]);
}

// ---------------- MFMA conv GEMM, latency-tiled ----------------
// Block: 4 waves x (MR*16) rows; cols: blockIdx.y * (NF*16). Per kb-step each
// wave batch-loads MR A-frags + NF B-frags (registers), then MR*NF MFMAs.
template<int K, int OUT, int NF, int MR>
__global__ __launch_bounds__(256)
void gemm_mfma(const ushort_t* __restrict__ A, const ushort_t* __restrict__ Wt,
               float* __restrict__ P, ushort_t* __restrict__ Qb, int n) {
    constexpr int KB = K / 32;
    const int wave = threadIdx.x >> 6;
    const int lane = threadIdx.x & 63;
    const int lr = lane & 15;
    const int kg = lane >> 4;
    const int row0 = (blockIdx.x * 4 + wave) * (MR * 16);
    const int col0 = blockIdx.y * (NF * 16);

    f32x4 acc[MR][NF];
#pragma unroll
    for (int m = 0; m < MR; ++m)
#pragma unroll
        for (int f = 0; f < NF; ++f) acc[m][f] = (f32x4)(0.f);

    const ushort_t* Ap[MR];
#pragma unroll
    for (int m = 0; m < MR; ++m) {
        int arow = row0 + m * 16 + lr;
        if (arow >= n) arow = n - 1;
        Ap[m] = A + (size_t)arow * K + kg * 8;
    }
    const ushort_t* Bp = Wt + (size_t)(col0 + lr) * K + kg * 8;

#pragma unroll
    for (int kb = 0; kb < KB; ++kb) {
        bf16x8 af[MR];
#pragma unroll
        for (int m = 0; m < MR; ++m) af[m] = *(const bf16x8*)(Ap[m] + kb * 32);
        bf16x8 bfv[NF];
#pragma unroll
        for (int f = 0; f < NF; ++f)
            bfv[f] = *(const bf16x8*)(Bp + (size_t)f * 16 * K + kb * 32);
#pragma unroll
        for (int f = 0; f < NF; ++f)
#pragma unroll
            for (int m = 0; m < MR; ++m)
                acc[m][f] = __builtin_amdgcn_mfma_f32_16x16x32_bf16(af[m], bfv[f], acc[m][f], 0, 0, 0);
    }

    // D layout: col = lr, row = kg*4 + r
#pragma unroll
    for (int m = 0; m < MR; ++m) {
#pragma unroll
        for (int f = 0; f < NF; ++f) {
#pragma unroll
            for (int r = 0; r < 4; ++r) {
                int row = row0 + m * 16 + kg * 4 + r;
                if (row < n) {
                    int c = col0 + f * 16 + lr;
                    float v = acc[m][f][r];
                    if (c < OUT) P[(size_t)row * OUT + c] = v;
                    else Qb[(size_t)row * OUT + (c - OUT)] = f2bf(v);
                }
            }
        }
    }
}

// ---------------- MFMA head, retiled: partial fc2 -> atomicAdd(hacc) ----------
// grid.y=2 col halves; per wave 16 rows x 128 cols (NF=8).
__global__ __launch_bounds__(256)
void head_mfma(const ushort_t* __restrict__ H, const ushort_t* __restrict__ Wf1t,
               const float* __restrict__ bf1, const float* __restrict__ Wf2,
               float* __restrict__ hacc, int n) {
    const int wave = threadIdx.x >> 6;
    const int lane = threadIdx.x & 63;
    const int row0 = (blockIdx.x * 4 + wave) * 16;
    const int col0 = blockIdx.y * 128;
    const int lr = lane & 15;
    const int kg = lane >> 4;

    f32x4 acc[8];
#pragma unroll
    for (int i = 0; i < 8; ++i) acc[i] = (f32x4)(0.f);

    int arow = row0 + lr;
    if (arow >= n) arow = n - 1;
    const ushort_t* Aptr = H + (size_t)arow * 256 + kg * 8;
    const ushort_t* Bp = Wf1t + (size_t)(col0 + lr) * 256 + kg * 8;

#pragma unroll
    for (int kb = 0; kb < 8; ++kb) {
        bf16x8 afrag = *(const bf16x8*)(Aptr + kb * 32);
        bf16x8 bfv[8];
#pragma unroll
        for (int nf = 0; nf < 8; ++nf)
            bfv[nf] = *(const bf16x8*)(Bp + (size_t)nf * 16 * 256 + kb * 32);
#pragma unroll
        for (int nf = 0; nf < 8; ++nf)
            acc[nf] = __builtin_amdgcn_mfma_f32_16x16x32_bf16(afrag, bfv[nf], acc[nf], 0, 0, 0);
    }

    // partial fc2 over this col-half, reduce across the 16 lr lanes
    float part[4] = {0.f, 0.f, 0.f, 0.f};
#pragma unroll
    for (int nf = 0; nf < 8; ++nf) {
        int c = col0 + nf * 16 + lr;
        float w2 = Wf2[c];
        float bb = bf1[c];
#pragma unroll
        for (int r = 0; r < 4; ++r)
            part[r] = fmaf(fmaxf(acc[nf][r] + bb, 0.f), w2, part[r]);
    }
#pragma unroll
    for (int s = 1; s < 16; s <<= 1) {
#pragma unroll
        for (int r = 0; r < 4; ++r) part[r] += __shfl_xor(part[r], s, 16);
    }
    if (lr == 0) {
#pragma unroll
        for (int r = 0; r < 4; ++r) {
            int row = row0 + kg * 4 + r;
            if (row < n) atomicAdd(&hacc[row], part[r]);
        }
    }
}

__global__ void zerof_kernel(float* __restrict__ p, int n) {
    int i = blockIdx.x * blockDim.x + threadIdx.x;
    int s = gridDim.x * blockDim.x;
    for (; i < n; i += s) p[i] = 0.f;
}

__global__ void sigmoid_kernel(const float* __restrict__ hacc, const float* __restrict__ bf2,
                               float* __restrict__ out, int n) {
    int i = blockIdx.x * blockDim.x + threadIdx.x;
    int s = gridDim.x * blockDim.x;
    float b = bf2[0];
    for (; i < n; i += s) out[i] = 1.f / (1.f + expf(-(hacc[i] + b)));
}

// ---------------- segment-max over Qb (bf16) + combine -> H bf16 ----------------
template<int OUT>
__global__ __launch_bounds__(256, 8)
void segmax_combine(const float* __restrict__ P, const ushort_t* __restrict__ Qb,
                    const int* __restrict__ rowptr, const int* __restrict__ col,
                    const float* __restrict__ bias, ushort_t* __restrict__ Hout, int n) {
    constexpr int G = OUT / 8;
    constexpr int NPB = 256 / G;
    const int gid = threadIdx.x / G;
    const int lane = threadIdx.x % G;
    const int i = blockIdx.x * NPB + gid;
    if (i >= n) return;

    const int r0 = rowptr[i];
    const int r1 = rowptr[i + 1];
    const int c8 = lane * 8;

    float m[8];
#pragma unroll
    for (int j = 0; j < 8; ++j) m[j] = -INFINITY;

    auto domax = [&](uint4 q) {
        m[0] = fmaxf(m[0], __uint_as_float(q.x << 16));
        m[1] = fmaxf(m[1], __uint_as_float(q.x & 0xffff0000u));
        m[2] = fmaxf(m[2], __uint_as_float(q.y << 16));
        m[3] = fmaxf(m[3], __uint_as_float(q.y & 0xffff0000u));
        m[4] = fmaxf(m[4], __uint_as_float(q.z << 16));
        m[5] = fmaxf(m[5], __uint_as_float(q.z & 0xffff0000u));
        m[6] = fmaxf(m[6], __uint_as_float(q.w << 16));
        m[7] = fmaxf(m[7], __uint_as_float(q.w & 0xffff0000u));
    };

    int r = r0;
    for (; r + 1 < r1; r += 2) {
        int s0 = col[r];
        int s1 = col[r + 1];
        uint4 qa = *(const uint4*)(Qb + (size_t)s0 * OUT + c8);
        uint4 qb = *(const uint4*)(Qb + (size_t)s1 * OUT + c8);
        domax(qa);
        domax(qb);
    }
    if (r < r1) {
        int s0 = col[r];
        domax(*(const uint4*)(Qb + (size_t)s0 * OUT + c8));
    }

    const float4 p0 = *(const float4*)(P + (size_t)i * OUT + c8);
    const float4 p1 = *(const float4*)(P + (size_t)i * OUT + c8 + 4);
    const float4 b0 = *(const float4*)(bias + c8);
    const float4 b1 = *(const float4*)(bias + c8 + 4);

    float h[8];
    h[0] = fmaxf(p0.x + b0.x + m[0], 0.f);
    h[1] = fmaxf(p0.y + b0.y + m[1], 0.f);
    h[2] = fmaxf(p0.z + b0.z + m[2], 0.f);
    h[3] = fmaxf(p0.w + b0.w + m[3], 0.f);
    h[4] = fmaxf(p1.x + b1.x + m[4], 0.f);
    h[5] = fmaxf(p1.y + b1.y + m[5], 0.f);
    h[6] = fmaxf(p1.z + b1.z + m[6], 0.f);
    h[7] = fmaxf(p1.w + b1.w + m[7], 0.f);

    uint4 o;
    o.x = pack2bf(h[0], h[1]);
    o.y = pack2bf(h[2], h[3]);
    o.z = pack2bf(h[4], h[5]);
    o.w = pack2bf(h[6], h[7]);
    *(uint4*)(Hout + (size_t)i * OUT + c8) = o;
}

// ---------------- launch ----------------
extern "C" void kernel_launch(void* const* d_in, const int* in_sizes, int n_in,
                              void* d_out, int out_size, void* d_ws, size_t ws_size,
                              hipStream_t stream) {
    const float* X   = (const float*)d_in[0];
    const int*   ei  = (const int*)d_in[1];
    const float* W1  = (const float*)d_in[2];
    const float* b1  = (const float*)d_in[3];
    const float* W2  = (const float*)d_in[4];
    const float* b2  = (const float*)d_in[5];
    const float* W3  = (const float*)d_in[6];
    const float* b3  = (const float*)d_in[7];
    const float* Wf1 = (const float*)d_in[8];
    const float* bf1 = (const float*)d_in[9];
    const float* Wf2 = (const float*)d_in[10];
    const float* bf2 = (const float*)d_in[11];
    float* out = (float*)d_out;

    int istride = (in_sizes[1] == 4 * NE) ? 2 : 1;
    const int* esrc = ei;
    const int* edst = ei + (size_t)NE * istride;

    // workspace layout
    float*    P      = (float*)d_ws;                        // 50000*256 f32
    ushort_t* Qb     = (ushort_t*)(P + (size_t)NN * 256);   // 50000*256 bf16
    ushort_t* Ha     = Qb + (size_t)NN * 256;               // 50000*256 bf16
    ushort_t* Hb     = Ha + (size_t)NN * 256;               // 50000*256 bf16
    int*      rowptr = (int*)(Hb + (size_t)NN * 256);
    int*      deg    = rowptr + (NN + 8);
    int*      col    = deg + NN;
    int*      bsum   = col + NE;
    int*      boff   = bsum + 256;
    ushort_t* Wt1    = (ushort_t*)(boff + 256);             // 128*32 bf16
    ushort_t* Wt2    = Wt1 + 128 * 32;                      // 256*64
    ushort_t* Wt3    = Wt2 + 256 * 64;                      // 512*128
    ushort_t* Wf1t   = Wt3 + 512 * 128;                     // 256*256
    ushort_t* Xb     = Wf1t + 256 * 256;                    // 50000*32 bf16
    float*    hacc   = (float*)(Xb + (size_t)NN * 32);      // 50000 f32

    const int NB = (NN + 255) / 256;

    // ---- CSR build ----
    zeroi_kernel<<<256, 256, 0, stream>>>(deg, NN);
    hist_kernel<<<1024, 256, 0, stream>>>(edst, istride, deg, NE);
    scan_reduce<<<NB, 256, 0, stream>>>(deg, bsum, NN);
    scan_tops<<<1, 256, 0, stream>>>(bsum, boff, rowptr, NB, NN);
    scan_apply<<<NB, 256, 0, stream>>>(deg, boff, rowptr, NN);
    scatter_kernel<<<1024, 256, 0, stream>>>(esrc, edst, istride, deg, col, NE);

    // ---- weight / input prep ----
    prepwt1_kernel<<<(128 * 32 + 255) / 256, 256, 0, stream>>>(W1, Wt1);
    prepwt_kernel<<<(2 * 128 * 64 + 255) / 256, 256, 0, stream>>>(W2, Wt2, 64, 128);
    prepwt_kernel<<<(2 * 256 * 128 + 255) / 256, 256, 0, stream>>>(W3, Wt3, 128, 256);
    transw_kernel<<<(256 * 256 + 255) / 256, 256, 0, stream>>>(Wf1, Wf1t, 256, 256);
    xpad_kernel<<<1024, 256, 0, stream>>>(X, Xb, NN);

    const int GB = (NN + 127) / 128;   // row blocks for gemm_mfma (128 rows/block)

    // ---- layer 1: Xb[N,32] -> P[.,64],Qb[.,64] -> Ha bf16[.,64] ----
    {
        dim3 g(GB, 1);
        gemm_mfma<32, 64, 8, 2><<<g, 256, 0, stream>>>(Xb, Wt1, P, Qb, NN);
    }
    segmax_combine<64><<<(NN * 8 + 255) / 256, 256, 0, stream>>>(P, Qb, rowptr, col, b1, Ha, NN);

    // ---- layer 2: Ha -> P[.,128],Qb[.,128] -> Hb bf16[.,128] ----
    {
        dim3 g(GB, 2);
        gemm_mfma<64, 128, 8, 2><<<g, 256, 0, stream>>>(Ha, Wt2, P, Qb, NN);
    }
    segmax_combine<128><<<(NN * 16 + 255) / 256, 256, 0, stream>>>(P, Qb, rowptr, col, b2, Hb, NN);

    // ---- layer 3: Hb -> P[.,256],Qb[.,256] -> Ha bf16[.,256] ----
    {
        dim3 g(GB, 4);
        gemm_mfma<128, 256, 8, 2><<<g, 256, 0, stream>>>(Hb, Wt3, P, Qb, NN);
    }
    segmax_combine<256><<<(NN * 32 + 255) / 256, 256, 0, stream>>>(P, Qb, rowptr, col, b3, Ha, NN);

    // ---- MLP head: Ha -> hacc -> out ----
    zerof_kernel<<<64, 256, 0, stream>>>(hacc, NN);
    {
        dim3 g((NN + 63) / 64, 2);
        head_mfma<<<g, 256, 0, stream>>>(Ha, Wf1t, bf1, Wf2, hacc, NN);
    }
    sigmoid_kernel<<<64, 256, 0, stream>>>(hacc, bf2, out, NN);
}